// Round 3
// baseline (917.831 us; speedup 1.0000x reference)
//
#include <hip/hip_runtime.h>
#include <stdint.h>

#define MAX_DEG   10
#define DEG_COUNT 30000
#define N_ATOMS   330000      // 11 * 30000
#define NF        128
#define BATCH     128
#define NSLICES   512         // k_segsum grid = partial-slice count

typedef __attribute__((ext_vector_type(8))) short bf16x8;   // 8 bf16 (4 VGPRs)
typedef __attribute__((ext_vector_type(4))) float f32x4;

__device__ __forceinline__ float bf2f(unsigned short h) {
  union { unsigned u; float f; } v; v.u = ((unsigned)h) << 16; return v.f;
}
__device__ __forceinline__ unsigned short f2bf(float f) {
  union { float f; unsigned u; } v; v.f = f;
  unsigned u = v.u;
  unsigned r = (u + 0x7fffu + ((u >> 16) & 1u)) >> 16;   // RNE
  return (unsigned short)r;
}

struct AdjPtrs { const int* p[10]; };

#define NEG_INF_BITS 0xFF800000

// ---------------------------------------------------------------------------
// K_init: -inf gmax (ws is re-poisoned before every launch).
// ---------------------------------------------------------------------------
__global__ __launch_bounds__(256) void k_init(int* __restrict__ gmax) {
  int i = blockIdx.x * 256 + threadIdx.x;
  if (i < BATCH * 128) gmax[i] = (int)NEG_INF_BITS;
}

// ---------------------------------------------------------------------------
// K0: cast fp32 atoms -> bf16 copy (GEMM A-source + gather source, L3-resident)
// ---------------------------------------------------------------------------
__global__ __launch_bounds__(256) void k_cast(const float4* __restrict__ src,
                                              ushort4* __restrict__ dst) {
  size_t i = (size_t)blockIdx.x * 256 + threadIdx.x;   // one float4 -> ushort4
  float4 v = src[i];
  ushort4 o;
  o.x = f2bf(v.x); o.y = f2bf(v.y); o.z = f2bf(v.z); o.w = f2bf(v.w);
  dst[i] = o;
}

// ---------------------------------------------------------------------------
// K1a: build BcatT[d][n][k] (bf16), n,k in [0,256), from fp32 W.
// Virtual B[d][k][n]: k<128 -> neigh (Wrel | 0), k>=128 -> self (Wself | Wg)
// ---------------------------------------------------------------------------
__global__ __launch_bounds__(256) void k_build_b(const float* __restrict__ W,
                                                 unsigned short* __restrict__ BcatT) {
  int idx = blockIdx.x * 256 + threadIdx.x;
  if (idx >= 11 * 256 * 256) return;
  int d = idx >> 16;
  int rem = idx & 65535;
  int n = rem >> 8;
  int k = rem & 255;
  float v = 0.f;
  if (k < 128) {
    if (n < 128 && d >= 1) v = W[(2 * (d - 1)) * 16384 + k * 128 + n];
  } else {
    int ks = k - 128;
    if (n < 128) { int wi = (d >= 1) ? (2 * d - 1) : 20; v = W[wi * 16384 + ks * 128 + n]; }
    else         { int wi = (d >= 1) ? (20 + d)   : 31; v = W[wi * 16384 + ks * 128 + (n - 128)]; }
  }
  BcatT[idx] = f2bf(v);   // idx == d*65536 + n*256 + k
}

// K1b: biascat[d][n] f32: n<128 -> b_rel + b_self (activated), n>=128 -> b_gather
__global__ __launch_bounds__(256) void k_build_bias(const float* __restrict__ b,
                                                    float* __restrict__ biascat) {
  int idx = blockIdx.x * 256 + threadIdx.x;
  if (idx >= 11 * 256) return;
  int d = idx >> 8, n = idx & 255;
  float f;
  if (n < 128) {
    if (d >= 1) f = b[(2 * (d - 1)) * 128 + n] + b[(2 * d - 1) * 128 + n];
    else        f = b[20 * 128 + n];
  } else {
    int j = n - 128;
    f = (d >= 1) ? b[(20 + d) * 128 + j] : b[31 * 128 + j];
  }
  biascat[idx] = f;
}

// ---------------------------------------------------------------------------
// K2: neighbor sums from bf16 atom copy. One wave per atom row; lane = 2 cols.
// deg-0 rows written as zeros (B zero-block makes them inert).
// ---------------------------------------------------------------------------
__global__ __launch_bounds__(256) void k_nsum(const unsigned* __restrict__ atomsU,
                                              AdjPtrs adj,
                                              unsigned* __restrict__ nsumU) {
  int wave = threadIdx.x >> 6;
  int lane = threadIdx.x & 63;
  int row = blockIdx.x * 4 + wave;
  if (row >= N_ATOMS) return;
  int d = row / DEG_COUNT;
  if (d == 0) { nsumU[row * 64 + lane] = 0u; return; }
  int r = row - d * DEG_COUNT;
  const int* a = adj.p[d - 1];
  float s0 = 0.f, s1 = 0.f;
  for (int j = 0; j < d; ++j) {
    int nbr = a[r * d + j];
    unsigned x = atomsU[nbr * 64 + lane];
    s0 += bf2f((unsigned short)(x & 0xffff));
    s1 += bf2f((unsigned short)(x >> 16));
  }
  nsumU[row * 64 + lane] = (unsigned)f2bf(s0) | ((unsigned)f2bf(s1) << 16);
}

// ---------------------------------------------------------------------------
// K3: barrier-free streaming MFMA GEMM (unchanged from round 2).
// ---------------------------------------------------------------------------
__global__ __launch_bounds__(512, 2) void k_gemm(
    const unsigned short* __restrict__ atomsBf,
    const unsigned short* __restrict__ nsum,
    const unsigned short* __restrict__ BcatT,    // [11][256][256] n-major
    const float* __restrict__ biascat,           // [11][256]
    const float* __restrict__ gamma,
    const float* __restrict__ beta,
    float* __restrict__ out0,                    // xn FINAL (fp32)
    unsigned short* __restrict__ gath)           // gathered ws (bf16)
{
  const int d = blockIdx.y;
  const int rowTile = blockIdx.x;
  const int tid = threadIdx.x;
  const int lane = tid & 63;
  const int wave = tid >> 6;          // 0..7
  const int m16 = lane & 15;
  const int g = lane >> 4;            // k-group 0..3

  __shared__ unsigned short Bs[256 * 256];   // 128 KiB, swizzled rows of 512B

  const unsigned short* Bd = BcatT + d * 65536;

  // ---- stage B: 512 threads x 16 x 16B = 128KB, swizzled dest ----
#pragma unroll
  for (int it = 0; it < 16; ++it) {
    int flat = it * 512 + tid;        // chunk of 16B; 32 chunks per row
    int row = flat >> 5;
    int c = flat & 31;
    uint4 v = *(const uint4*)(Bd + row * 256 + c * 8);
    int kb = (c * 16) ^ ((row & 7) << 4);
    *(uint4*)((char*)Bs + row * 512 + kb) = v;
  }

  // ---- hoist A-frag loads for both 16-row chunks (hide under barrier) ----
  const int rowBase0 = rowTile * 256 + wave * 32;
  bf16x8 af0[8], af1[8];
  {
    int rbL = rowBase0 + m16; if (rbL > DEG_COUNT - 1) rbL = DEG_COUNT - 1;
    size_t gr = (size_t)d * DEG_COUNT + rbL;
#pragma unroll
    for (int ks = 0; ks < 4; ++ks)
      af0[ks] = *(const bf16x8*)(nsum + gr * 128 + ks * 32 + g * 8);
#pragma unroll
    for (int ks = 4; ks < 8; ++ks)
      af0[ks] = *(const bf16x8*)(atomsBf + gr * 128 + (ks - 4) * 32 + g * 8);
  }
  {
    int rbL = rowBase0 + 16 + m16; if (rbL > DEG_COUNT - 1) rbL = DEG_COUNT - 1;
    size_t gr = (size_t)d * DEG_COUNT + rbL;
#pragma unroll
    for (int ks = 0; ks < 4; ++ks)
      af1[ks] = *(const bf16x8*)(nsum + gr * 128 + ks * 32 + g * 8);
#pragma unroll
    for (int ks = 4; ks < 8; ++ks)
      af1[ks] = *(const bf16x8*)(atomsBf + gr * 128 + (ks - 4) * 32 + g * 8);
  }

  // ---- per-lane column constants ----
  float bias_[16], gam[8], bet[8];
#pragma unroll
  for (int ct = 0; ct < 16; ++ct) bias_[ct] = biascat[d * 256 + ct * 16 + m16];
#pragma unroll
  for (int ct = 0; ct < 8; ++ct) {
    gam[ct] = gamma[ct * 16 + m16];
    bet[ct] = beta[ct * 16 + m16];
  }

  __syncthreads();   // the only block-wide barrier

  const int ldsMask = (m16 & 7) << 4;

#pragma unroll
  for (int sub = 0; sub < 2; ++sub) {
    const int rowBase = rowBase0 + sub * 16;
    f32x4 acc[16];
#pragma unroll
    for (int ct = 0; ct < 16; ++ct) acc[ct] = (f32x4){0.f, 0.f, 0.f, 0.f};

#pragma unroll
    for (int ct = 0; ct < 16; ++ct) {
      const char* bbase = (const char*)Bs + (ct * 16 + m16) * 512;
      bf16x8 bf[8];
#pragma unroll
      for (int ks = 0; ks < 8; ++ks)
        bf[ks] = *(const bf16x8*)(bbase + ((ks * 64 + g * 16) ^ ldsMask));
#pragma unroll
      for (int ks = 0; ks < 8; ++ks) {
        bf16x8 a = (sub == 0) ? af0[ks] : af1[ks];
        acc[ct] = __builtin_amdgcn_mfma_f32_16x16x32_bf16(a, bf[ks], acc[ct], 0, 0, 0);
      }
    }

    // ---- epilogue: bias, LN over cols 0..127, stores (no barriers) ----
#pragma unroll
    for (int ct = 0; ct < 16; ++ct)
#pragma unroll
      for (int r = 0; r < 4; ++r) acc[ct][r] += bias_[ct];

    float s[4], qq[4];
#pragma unroll
    for (int r = 0; r < 4; ++r) {
      s[r] = 0.f; qq[r] = 0.f;
#pragma unroll
      for (int ct = 0; ct < 8; ++ct) {
        float v = acc[ct][r];
        s[r] += v; qq[r] += v * v;
      }
    }
#pragma unroll
    for (int off = 8; off >= 1; off >>= 1) {
#pragma unroll
      for (int r = 0; r < 4; ++r) {
        s[r]  += __shfl_xor(s[r],  off, 64);
        qq[r] += __shfl_xor(qq[r], off, 64);
      }
    }

#pragma unroll
    for (int r = 0; r < 4; ++r) {
      int rb = rowBase + g * 4 + r;
      float mean = s[r] * (1.0f / 128.0f);
      float var  = qq[r] * (1.0f / 128.0f) - mean * mean;
      float inv  = 1.0f / (sqrtf(var + 1e-5f) + 1e-5f);   // ref: sqrt(var+eps)+eps
      if (rb < DEG_COUNT) {
        size_t grow = (size_t)d * DEG_COUNT + rb;
#pragma unroll
        for (int ct = 0; ct < 8; ++ct)
          out0[grow * 128 + ct * 16 + m16] = gam[ct] * ((acc[ct][r] - mean) * inv) + bet[ct];
#pragma unroll
        for (int ct = 8; ct < 16; ++ct)
          gath[grow * 128 + (ct - 8) * 16 + m16] = f2bf(acc[ct][r]);
      }
    }
  }
}

// ---------------------------------------------------------------------------
// K4: read-only segment-max of final xn via per-block LDS table + monotonic
// int atomics (native int RMW, no CAS loop).
// ---------------------------------------------------------------------------
__global__ __launch_bounds__(512) void k_max(
    const float2* __restrict__ xnV,
    const int* __restrict__ membership,
    int* __restrict__ gmax)
{
  __shared__ int pmax[BATCH * 128];
  int tid = threadIdx.x;
  for (int i = tid; i < BATCH * 128; i += 512) pmax[i] = (int)NEG_INF_BITS;
  __syncthreads();
  int wave = tid >> 6, lane = tid & 63;
  const int rowsPerBlock = (N_ATOMS + gridDim.x - 1) / gridDim.x;
  int r0 = blockIdx.x * rowsPerBlock;
  int r1 = min(r0 + rowsPerBlock, N_ATOMS);
  for (int r = r0 + wave; r < r1; r += 8) {
    float2 x = xnV[(size_t)r * 64 + lane];
    int m = membership[r];
    int idx = m * 128 + lane * 2;
    if (x.x >= 0.f) atomicMax(&pmax[idx], __float_as_int(x.x));
    else            atomicMin((unsigned*)&pmax[idx], __float_as_uint(x.x));
    if (x.y >= 0.f) atomicMax(&pmax[idx + 1], __float_as_int(x.y));
    else            atomicMin((unsigned*)&pmax[idx + 1], __float_as_uint(x.y));
  }
  __syncthreads();
  for (int i = tid; i < BATCH * 128; i += 512) {
    int v = pmax[i];
    if (v != (int)NEG_INF_BITS) {
      if (v >= 0) atomicMax(&gmax[i], v);
      else        atomicMin((unsigned*)&gmax[i], (unsigned)v);
    }
  }
}

// ---------------------------------------------------------------------------
// K5: per-block LDS segment-sum of gathered (bf16) -> plain-store partial
// slice (NO global f32 atomics: HIP atomicAdd(float*) global is a CAS loop
// without -munsafe-fp-atomics; 8.4M contended CAS was 235us).
// LDS layout permuted so both ds_add_f32 per lane are 2-way bank (free):
//   col 2l -> offset l, col 2l+1 -> offset 64+l. Copy-out de-permutes.
// ---------------------------------------------------------------------------
__global__ __launch_bounds__(512) void k_segsum(
    const unsigned* __restrict__ gathU,
    const int* __restrict__ membership,
    float* __restrict__ partial)            // [NSLICES][BATCH*128]
{
  __shared__ float psum[BATCH * 128];
  int tid = threadIdx.x;
  for (int i = tid; i < BATCH * 128; i += 512) psum[i] = 0.f;
  __syncthreads();
  int wave = tid >> 6, lane = tid & 63;
  const int rowsPerBlock = (N_ATOMS + NSLICES - 1) / NSLICES;
  int r0 = blockIdx.x * rowsPerBlock;
  int r1 = min(r0 + rowsPerBlock, N_ATOMS);
  for (int r = r0 + wave; r < r1; r += 8) {
    unsigned x = gathU[(size_t)r * 64 + lane];
    int m = membership[r];
    atomicAdd(&psum[m * 128 + lane],      bf2f((unsigned short)(x & 0xffff)));   // col 2l
    atomicAdd(&psum[m * 128 + 64 + lane], bf2f((unsigned short)(x >> 16)));      // col 2l+1
  }
  __syncthreads();
  float* slice = partial + (size_t)blockIdx.x * (BATCH * 128);
  for (int i = tid; i < BATCH * 128; i += 512) {
    int c = i & 127;
    int off = (c >> 1) + (c & 1) * 64;      // de-permute
    slice[i] = psum[(i & ~127) + off];
  }
}

// K6: sum partial slices -> s; norm -> yn (out1); gmax -> g (out2). fp32.
__global__ __launch_bounds__(128) void k_final(
    const float* __restrict__ partial,      // [NSLICES][BATCH*128]
    const int* __restrict__ gmax,
    const float* __restrict__ gamma,
    const float* __restrict__ beta,
    float* __restrict__ out1,
    float* __restrict__ out2)
{
  int m = blockIdx.x;
  int j = threadIdx.x;
  const float* p = partial + m * 128 + j;
  float s0 = 0.f, s1 = 0.f, s2 = 0.f, s3 = 0.f;
#pragma unroll 4
  for (int sl = 0; sl < NSLICES; sl += 4) {
    s0 += p[(size_t)sl * 16384];
    s1 += p[(size_t)(sl + 1) * 16384];
    s2 += p[(size_t)(sl + 2) * 16384];
    s3 += p[(size_t)(sl + 3) * 16384];
  }
  float s = (s0 + s1) + (s2 + s3);
  out2[m * 128 + j] = __int_as_float(gmax[m * 128 + j]);

  float ws_ = s, wq = s * s;
#pragma unroll
  for (int off = 32; off >= 1; off >>= 1) {
    ws_ += __shfl_xor(ws_, off, 64);
    wq  += __shfl_xor(wq, off, 64);
  }
  __shared__ float red[4];
  int wave = j >> 6, lane = j & 63;
  if (lane == 0) { red[wave * 2] = ws_; red[wave * 2 + 1] = wq; }
  __syncthreads();
  float S = red[0] + red[2], Q = red[1] + red[3];
  float mean = S * (1.f / 128.f);
  float var = Q * (1.f / 128.f) - mean * mean;
  float inv = 1.f / (sqrtf(var + 1e-5f) + 1e-5f);
  float yn = gamma[j] * ((s - mean) * inv) + beta[j];
  out1[m * 128 + j] = yn;
}

// ---------------------------------------------------------------------------
extern "C" void kernel_launch(void* const* d_in, const int* in_sizes, int n_in,
                              void* d_out, int out_size, void* d_ws, size_t ws_size,
                              hipStream_t stream) {
  const float* atoms = (const float*)d_in[0];
  // d_in[1] = deg_slice (unused; buckets are static)
  const int* membership = (const int*)d_in[2];
  AdjPtrs adj;
  for (int i = 0; i < 10; ++i) adj.p[i] = (const int*)d_in[3 + i];
  const float* W     = (const float*)d_in[13];
  const float* b     = (const float*)d_in[14];
  const float* gamma = (const float*)d_in[15];
  const float* beta  = (const float*)d_in[16];

  char* ws = (char*)d_ws;
  size_t off = 0;
  unsigned short* atomsBf = (unsigned short*)(ws + off); off += (size_t)N_ATOMS * 128 * 2;
  unsigned short* nsum    = (unsigned short*)(ws + off); off += (size_t)N_ATOMS * 128 * 2;
  unsigned short* gath    = (unsigned short*)(ws + off); off += (size_t)N_ATOMS * 128 * 2;
  unsigned short* BcatT   = (unsigned short*)(ws + off); off += (size_t)11 * 256 * 256 * 2;
  float* biascat          = (float*)(ws + off);          off += (size_t)11 * 256 * 4;
  int*   gmax             = (int*)(ws + off);            off += (size_t)BATCH * 128 * 4;

  // partial slices reuse nsum's space (dead after k_gemm): 512*64KB = 32MB <= 84.5MB
  float* partial = (float*)nsum;

  float* out0 = (float*)d_out;
  float* out1 = out0 + (size_t)N_ATOMS * 128;
  float* out2 = out1 + 16384;

  hipLaunchKernelGGL(k_init, dim3((BATCH * 128 + 255) / 256), dim3(256), 0, stream, gmax);
  hipLaunchKernelGGL(k_cast, dim3(N_ATOMS * 128 / 4 / 256), dim3(256), 0, stream,
                     (const float4*)atoms, (ushort4*)atomsBf);
  hipLaunchKernelGGL(k_build_b, dim3((11 * 256 * 256 + 255) / 256), dim3(256), 0, stream, W, BcatT);
  hipLaunchKernelGGL(k_build_bias, dim3((11 * 256 + 255) / 256), dim3(256), 0, stream, b, biascat);
  hipLaunchKernelGGL(k_nsum, dim3(N_ATOMS / 4), dim3(256), 0, stream,
                     (const unsigned*)atomsBf, adj, (unsigned*)nsum);
  hipLaunchKernelGGL(k_gemm, dim3(118, 11), dim3(512), 0, stream,
                     atomsBf, nsum, BcatT, biascat, gamma, beta, out0, gath);
  hipLaunchKernelGGL(k_max, dim3(512), dim3(512), 0, stream,
                     (const float2*)out0, membership, gmax);
  hipLaunchKernelGGL(k_segsum, dim3(NSLICES), dim3(512), 0, stream,
                     (const unsigned*)gath, membership, partial);
  hipLaunchKernelGGL(k_final, dim3(128), dim3(128), 0, stream,
                     partial, gmax, gamma, beta, out1, out2);
}

// Round 4
// 910.738 us; speedup vs baseline: 1.0078x; 1.0078x over previous
//
#include <hip/hip_runtime.h>
#include <stdint.h>

#define MAX_DEG   10
#define DEG_COUNT 30000
#define N_ATOMS   330000      // 11 * 30000
#define NF        128
#define BATCH     128

typedef __attribute__((ext_vector_type(8))) short bf16x8;   // 8 bf16 (4 VGPRs)
typedef __attribute__((ext_vector_type(4))) float f32x4;

__device__ __forceinline__ float bf2f(unsigned short h) {
  union { unsigned u; float f; } v; v.u = ((unsigned)h) << 16; return v.f;
}
__device__ __forceinline__ unsigned short f2bf(float f) {
  union { float f; unsigned u; } v; v.f = f;
  unsigned u = v.u;
  unsigned r = (u + 0x7fffu + ((u >> 16) & 1u)) >> 16;   // RNE
  return (unsigned short)r;
}

struct AdjPtrs { const int* p[10]; };

#define NEG_INF_BITS 0xFF800000

// ---------------------------------------------------------------------------
// K0: cast fp32 atoms -> bf16 copy (GEMM A-source + gather source, L3-resident)
// ---------------------------------------------------------------------------
__global__ __launch_bounds__(256) void k_cast(const float4* __restrict__ src,
                                              ushort4* __restrict__ dst) {
  size_t i = (size_t)blockIdx.x * 256 + threadIdx.x;   // one float4 -> ushort4
  float4 v = src[i];
  ushort4 o;
  o.x = f2bf(v.x); o.y = f2bf(v.y); o.z = f2bf(v.z); o.w = f2bf(v.w);
  dst[i] = o;
}

// ---------------------------------------------------------------------------
// K1a: build BcatT[d][n][k] (bf16), n,k in [0,256), from fp32 W.
// Virtual B[d][k][n]: k<128 -> neigh (Wrel | 0), k>=128 -> self (Wself | Wg)
// ---------------------------------------------------------------------------
__global__ __launch_bounds__(256) void k_build_b(const float* __restrict__ W,
                                                 unsigned short* __restrict__ BcatT) {
  int idx = blockIdx.x * 256 + threadIdx.x;
  if (idx >= 11 * 256 * 256) return;
  int d = idx >> 16;
  int rem = idx & 65535;
  int n = rem >> 8;
  int k = rem & 255;
  float v = 0.f;
  if (k < 128) {
    if (n < 128 && d >= 1) v = W[(2 * (d - 1)) * 16384 + k * 128 + n];
  } else {
    int ks = k - 128;
    if (n < 128) { int wi = (d >= 1) ? (2 * d - 1) : 20; v = W[wi * 16384 + ks * 128 + n]; }
    else         { int wi = (d >= 1) ? (20 + d)   : 31; v = W[wi * 16384 + ks * 128 + (n - 128)]; }
  }
  BcatT[idx] = f2bf(v);   // idx == d*65536 + n*256 + k
}

// K1b: biascat[d][n] f32: n<128 -> b_rel + b_self (activated), n>=128 -> b_gather
__global__ __launch_bounds__(256) void k_build_bias(const float* __restrict__ b,
                                                    float* __restrict__ biascat) {
  int idx = blockIdx.x * 256 + threadIdx.x;
  if (idx >= 11 * 256) return;
  int d = idx >> 8, n = idx & 255;
  float f;
  if (n < 128) {
    if (d >= 1) f = b[(2 * (d - 1)) * 128 + n] + b[(2 * d - 1) * 128 + n];
    else        f = b[20 * 128 + n];
  } else {
    int j = n - 128;
    f = (d >= 1) ? b[(20 + d) * 128 + j] : b[31 * 128 + j];
  }
  biascat[idx] = f;
}

// ---------------------------------------------------------------------------
// K2: neighbor sums from bf16 atom copy. One wave per atom row; lane = 2 cols.
// deg-0 rows written as zeros (B zero-block makes them inert).
// ---------------------------------------------------------------------------
__global__ __launch_bounds__(256) void k_nsum(const unsigned* __restrict__ atomsU,
                                              AdjPtrs adj,
                                              unsigned* __restrict__ nsumU) {
  int wave = threadIdx.x >> 6;
  int lane = threadIdx.x & 63;
  int row = blockIdx.x * 4 + wave;
  if (row >= N_ATOMS) return;
  int d = row / DEG_COUNT;
  if (d == 0) { nsumU[row * 64 + lane] = 0u; return; }
  int r = row - d * DEG_COUNT;
  const int* a = adj.p[d - 1];
  float s0 = 0.f, s1 = 0.f;
  for (int j = 0; j < d; ++j) {
    int nbr = a[r * d + j];
    unsigned x = atomsU[nbr * 64 + lane];
    s0 += bf2f((unsigned short)(x & 0xffff));
    s1 += bf2f((unsigned short)(x >> 16));
  }
  nsumU[row * 64 + lane] = (unsigned)f2bf(s0) | ((unsigned)f2bf(s1) << 16);
}

// ---------------------------------------------------------------------------
// K3: barrier-free streaming MFMA GEMM (unchanged from round 2).
// ---------------------------------------------------------------------------
__global__ __launch_bounds__(512, 2) void k_gemm(
    const unsigned short* __restrict__ atomsBf,
    const unsigned short* __restrict__ nsum,
    const unsigned short* __restrict__ BcatT,    // [11][256][256] n-major
    const float* __restrict__ biascat,           // [11][256]
    const float* __restrict__ gamma,
    const float* __restrict__ beta,
    float* __restrict__ out0,                    // xn FINAL (fp32)
    unsigned short* __restrict__ gath)           // gathered ws (bf16)
{
  const int d = blockIdx.y;
  const int rowTile = blockIdx.x;
  const int tid = threadIdx.x;
  const int lane = tid & 63;
  const int wave = tid >> 6;          // 0..7
  const int m16 = lane & 15;
  const int g = lane >> 4;            // k-group 0..3

  __shared__ unsigned short Bs[256 * 256];   // 128 KiB, swizzled rows of 512B

  const unsigned short* Bd = BcatT + d * 65536;

  // ---- stage B: 512 threads x 16 x 16B = 128KB, swizzled dest ----
#pragma unroll
  for (int it = 0; it < 16; ++it) {
    int flat = it * 512 + tid;        // chunk of 16B; 32 chunks per row
    int row = flat >> 5;
    int c = flat & 31;
    uint4 v = *(const uint4*)(Bd + row * 256 + c * 8);
    int kb = (c * 16) ^ ((row & 7) << 4);
    *(uint4*)((char*)Bs + row * 512 + kb) = v;
  }

  // ---- hoist A-frag loads for both 16-row chunks (hide under barrier) ----
  const int rowBase0 = rowTile * 256 + wave * 32;
  bf16x8 af0[8], af1[8];
  {
    int rbL = rowBase0 + m16; if (rbL > DEG_COUNT - 1) rbL = DEG_COUNT - 1;
    size_t gr = (size_t)d * DEG_COUNT + rbL;
#pragma unroll
    for (int ks = 0; ks < 4; ++ks)
      af0[ks] = *(const bf16x8*)(nsum + gr * 128 + ks * 32 + g * 8);
#pragma unroll
    for (int ks = 4; ks < 8; ++ks)
      af0[ks] = *(const bf16x8*)(atomsBf + gr * 128 + (ks - 4) * 32 + g * 8);
  }
  {
    int rbL = rowBase0 + 16 + m16; if (rbL > DEG_COUNT - 1) rbL = DEG_COUNT - 1;
    size_t gr = (size_t)d * DEG_COUNT + rbL;
#pragma unroll
    for (int ks = 0; ks < 4; ++ks)
      af1[ks] = *(const bf16x8*)(nsum + gr * 128 + ks * 32 + g * 8);
#pragma unroll
    for (int ks = 4; ks < 8; ++ks)
      af1[ks] = *(const bf16x8*)(atomsBf + gr * 128 + (ks - 4) * 32 + g * 8);
  }

  // ---- per-lane column constants ----
  float bias_[16], gam[8], bet[8];
#pragma unroll
  for (int ct = 0; ct < 16; ++ct) bias_[ct] = biascat[d * 256 + ct * 16 + m16];
#pragma unroll
  for (int ct = 0; ct < 8; ++ct) {
    gam[ct] = gamma[ct * 16 + m16];
    bet[ct] = beta[ct * 16 + m16];
  }

  __syncthreads();   // the only block-wide barrier

  const int ldsMask = (m16 & 7) << 4;

#pragma unroll
  for (int sub = 0; sub < 2; ++sub) {
    const int rowBase = rowBase0 + sub * 16;
    f32x4 acc[16];
#pragma unroll
    for (int ct = 0; ct < 16; ++ct) acc[ct] = (f32x4){0.f, 0.f, 0.f, 0.f};

#pragma unroll
    for (int ct = 0; ct < 16; ++ct) {
      const char* bbase = (const char*)Bs + (ct * 16 + m16) * 512;
      bf16x8 bf[8];
#pragma unroll
      for (int ks = 0; ks < 8; ++ks)
        bf[ks] = *(const bf16x8*)(bbase + ((ks * 64 + g * 16) ^ ldsMask));
#pragma unroll
      for (int ks = 0; ks < 8; ++ks) {
        bf16x8 a = (sub == 0) ? af0[ks] : af1[ks];
        acc[ct] = __builtin_amdgcn_mfma_f32_16x16x32_bf16(a, bf[ks], acc[ct], 0, 0, 0);
      }
    }

    // ---- epilogue: bias, LN over cols 0..127, stores (no barriers) ----
#pragma unroll
    for (int ct = 0; ct < 16; ++ct)
#pragma unroll
      for (int r = 0; r < 4; ++r) acc[ct][r] += bias_[ct];

    float s[4], qq[4];
#pragma unroll
    for (int r = 0; r < 4; ++r) {
      s[r] = 0.f; qq[r] = 0.f;
#pragma unroll
      for (int ct = 0; ct < 8; ++ct) {
        float v = acc[ct][r];
        s[r] += v; qq[r] += v * v;
      }
    }
#pragma unroll
    for (int off = 8; off >= 1; off >>= 1) {
#pragma unroll
      for (int r = 0; r < 4; ++r) {
        s[r]  += __shfl_xor(s[r],  off, 64);
        qq[r] += __shfl_xor(qq[r], off, 64);
      }
    }

#pragma unroll
    for (int r = 0; r < 4; ++r) {
      int rb = rowBase + g * 4 + r;
      float mean = s[r] * (1.0f / 128.0f);
      float var  = qq[r] * (1.0f / 128.0f) - mean * mean;
      float inv  = 1.0f / (sqrtf(var + 1e-5f) + 1e-5f);   // ref: sqrt(var+eps)+eps
      if (rb < DEG_COUNT) {
        size_t grow = (size_t)d * DEG_COUNT + rb;
#pragma unroll
        for (int ct = 0; ct < 8; ++ct)
          out0[grow * 128 + ct * 16 + m16] = gam[ct] * ((acc[ct][r] - mean) * inv) + bet[ct];
#pragma unroll
        for (int ct = 8; ct < 16; ++ct)
          gath[grow * 128 + (ct - 8) * 16 + m16] = f2bf(acc[ct][r]);
      }
    }
  }
}

// ---------------------------------------------------------------------------
// Counting sort of atom indices by membership (static key in [0,128)).
// Scratch lives in atomsBf's space (dead after k_gemm), so these run post-GEMM.
// ---------------------------------------------------------------------------
__global__ __launch_bounds__(128) void k_zero(int* __restrict__ hist) {
  hist[threadIdx.x] = 0;
}

// 256 blocks x 256 thr, grid-stride; LDS bins then 128 global int atomics/block
__global__ __launch_bounds__(256) void k_hist(const int* __restrict__ membership,
                                              int* __restrict__ hist) {
  __shared__ int bins[BATCH];
  int tid = threadIdx.x;
  if (tid < BATCH) bins[tid] = 0;
  __syncthreads();
  for (int i = blockIdx.x * 256 + tid; i < N_ATOMS; i += 256 * 256)
    atomicAdd(&bins[membership[i]], 1);
  __syncthreads();
  if (tid < BATCH) atomicAdd(&hist[tid], bins[tid]);
}

// 1 block: exclusive scan of 128 bins -> base; cursor = base copy
__global__ __launch_bounds__(128) void k_scan(const int* __restrict__ hist,
                                              int* __restrict__ base,
                                              int* __restrict__ cursor) {
  __shared__ int b[BATCH];
  if (threadIdx.x == 0) {
    int a = 0;
    for (int i = 0; i < BATCH; ++i) { b[i] = a; a += hist[i]; }
  }
  __syncthreads();
  base[threadIdx.x] = b[threadIdx.x];
  cursor[threadIdx.x] = b[threadIdx.x];
}

// 330K native int atomics over 128 cursors; perm[pos] = row
__global__ __launch_bounds__(256) void k_scatter(const int* __restrict__ membership,
                                                 int* __restrict__ cursor,
                                                 int* __restrict__ perm) {
  for (int i = blockIdx.x * 256 + threadIdx.x; i < N_ATOMS; i += 256 * 256) {
    int m = membership[i];
    int pos = atomicAdd(&cursor[m], 1);
    perm[pos] = i;
  }
}

// ---------------------------------------------------------------------------
// K_reduce: fused segment-max(xn) + segment-sum(gath), atomic-free.
// 512 blocks = 128 molecules x 4 slices; 8 waves stride the slice's perm
// range; whole-row gathers (coalesced 512B/256B); register accumulation;
// LDS cross-wave reduce; writes tiny per-slice partials.
// ---------------------------------------------------------------------------
__global__ __launch_bounds__(512) void k_reduce(
    const float2* __restrict__ xnV,         // out0 as float2
    const unsigned* __restrict__ gathU,
    const int* __restrict__ perm,
    const int* __restrict__ base,
    const int* __restrict__ hist,
    float2* __restrict__ psum4,             // [4][128][64] float2
    float2* __restrict__ pmax4)             // [4][128][64] float2
{
  const int m = blockIdx.x >> 2;
  const int s = blockIdx.x & 3;
  const int b0 = base[m], cnt = hist[m];
  const int lo = b0 + (cnt * s) / 4;
  const int hi = b0 + (cnt * (s + 1)) / 4;
  const int wave = threadIdx.x >> 6, lane = threadIdx.x & 63;

  const float NEG_INF = __int_as_float((int)NEG_INF_BITS);
  float mx0 = NEG_INF, mx1 = NEG_INF, s0 = 0.f, s1 = 0.f;

#pragma unroll 4
  for (int i = lo + wave; i < hi; i += 8) {
    int r = perm[i];
    float2 x = xnV[(size_t)r * 64 + lane];
    unsigned gg = gathU[(size_t)r * 64 + lane];
    mx0 = fmaxf(mx0, x.x);
    mx1 = fmaxf(mx1, x.y);
    s0 += bf2f((unsigned short)(gg & 0xffff));
    s1 += bf2f((unsigned short)(gg >> 16));
  }

  __shared__ float2 sumT[8][64];
  __shared__ float2 maxT[8][64];
  sumT[wave][lane] = make_float2(s0, s1);
  maxT[wave][lane] = make_float2(mx0, mx1);
  __syncthreads();

  if (threadIdx.x < 64) {
    int l = threadIdx.x;
    float2 ss = sumT[0][l];
    float2 mm = maxT[0][l];
#pragma unroll
    for (int w = 1; w < 8; ++w) {
      float2 a = sumT[w][l]; ss.x += a.x; ss.y += a.y;
      float2 b = maxT[w][l]; mm.x = fmaxf(mm.x, b.x); mm.y = fmaxf(mm.y, b.y);
    }
    psum4[(s * 128 + m) * 64 + l] = ss;
    pmax4[(s * 128 + m) * 64 + l] = mm;
  }
}

// K6: merge 4 slices; norm sum -> yn (out1); max -> g (out2). fp32.
__global__ __launch_bounds__(128) void k_final(
    const float* __restrict__ psum4,        // [4][128][128]
    const float* __restrict__ pmax4,
    const float* __restrict__ gamma,
    const float* __restrict__ beta,
    float* __restrict__ out1,
    float* __restrict__ out2)
{
  int m = blockIdx.x;
  int j = threadIdx.x;
  float s = 0.f, g = __int_as_float((int)NEG_INF_BITS);
#pragma unroll
  for (int sl = 0; sl < 4; ++sl) {
    s += psum4[(sl * 128 + m) * 128 + j];
    g = fmaxf(g, pmax4[(sl * 128 + m) * 128 + j]);
  }
  out2[m * 128 + j] = g;

  float ws_ = s, wq = s * s;
#pragma unroll
  for (int off = 32; off >= 1; off >>= 1) {
    ws_ += __shfl_xor(ws_, off, 64);
    wq  += __shfl_xor(wq, off, 64);
  }
  __shared__ float red[4];
  int wave = j >> 6, lane = j & 63;
  if (lane == 0) { red[wave * 2] = ws_; red[wave * 2 + 1] = wq; }
  __syncthreads();
  float S = red[0] + red[2], Q = red[1] + red[3];
  float mean = S * (1.f / 128.f);
  float var = Q * (1.f / 128.f) - mean * mean;
  float inv = 1.f / (sqrtf(var + 1e-5f) + 1e-5f);
  float yn = gamma[j] * ((s - mean) * inv) + beta[j];
  out1[m * 128 + j] = yn;
}

// ---------------------------------------------------------------------------
extern "C" void kernel_launch(void* const* d_in, const int* in_sizes, int n_in,
                              void* d_out, int out_size, void* d_ws, size_t ws_size,
                              hipStream_t stream) {
  const float* atoms = (const float*)d_in[0];
  // d_in[1] = deg_slice (unused; buckets are static)
  const int* membership = (const int*)d_in[2];
  AdjPtrs adj;
  for (int i = 0; i < 10; ++i) adj.p[i] = (const int*)d_in[3 + i];
  const float* W     = (const float*)d_in[13];
  const float* b     = (const float*)d_in[14];
  const float* gamma = (const float*)d_in[15];
  const float* beta  = (const float*)d_in[16];

  char* ws = (char*)d_ws;
  size_t off = 0;
  unsigned short* atomsBf = (unsigned short*)(ws + off); off += (size_t)N_ATOMS * 128 * 2;
  unsigned short* nsum    = (unsigned short*)(ws + off); off += (size_t)N_ATOMS * 128 * 2;
  unsigned short* gath    = (unsigned short*)(ws + off); off += (size_t)N_ATOMS * 128 * 2;
  unsigned short* BcatT   = (unsigned short*)(ws + off); off += (size_t)11 * 256 * 256 * 2;
  float* biascat          = (float*)(ws + off);          off += (size_t)11 * 256 * 4;

  // Sort + reduction scratch reuses atomsBf's space (dead after k_gemm):
  char* scr = (char*)atomsBf;
  int* perm   = (int*)(scr);                       // 1.32 MB
  int* hist   = (int*)(scr + 2 * 1024 * 1024);     // 512 B
  int* base_  = (int*)(scr + 2 * 1024 * 1024 + 1024);
  int* cursor = (int*)(scr + 2 * 1024 * 1024 + 2048);
  float* psum4 = (float*)(scr + 3 * 1024 * 1024);  // 256 KB
  float* pmax4 = (float*)(scr + 3 * 1024 * 1024 + 256 * 1024);

  float* out0 = (float*)d_out;
  float* out1 = out0 + (size_t)N_ATOMS * 128;
  float* out2 = out1 + 16384;

  hipLaunchKernelGGL(k_cast, dim3(N_ATOMS * 128 / 4 / 256), dim3(256), 0, stream,
                     (const float4*)atoms, (ushort4*)atomsBf);
  hipLaunchKernelGGL(k_build_b, dim3((11 * 256 * 256 + 255) / 256), dim3(256), 0, stream, W, BcatT);
  hipLaunchKernelGGL(k_build_bias, dim3((11 * 256 + 255) / 256), dim3(256), 0, stream, b, biascat);
  hipLaunchKernelGGL(k_nsum, dim3(N_ATOMS / 4), dim3(256), 0, stream,
                     (const unsigned*)atomsBf, adj, (unsigned*)nsum);
  hipLaunchKernelGGL(k_gemm, dim3(118, 11), dim3(512), 0, stream,
                     atomsBf, nsum, BcatT, biascat, gamma, beta, out0, gath);
  // counting sort (scratch overlays dead atomsBf)
  hipLaunchKernelGGL(k_zero, dim3(1), dim3(128), 0, stream, hist);
  hipLaunchKernelGGL(k_hist, dim3(256), dim3(256), 0, stream, membership, hist);
  hipLaunchKernelGGL(k_scan, dim3(1), dim3(128), 0, stream, hist, base_, cursor);
  hipLaunchKernelGGL(k_scatter, dim3(256), dim3(256), 0, stream, membership, cursor, perm);
  // fused atomic-free segment max + sum
  hipLaunchKernelGGL(k_reduce, dim3(512), dim3(512), 0, stream,
                     (const float2*)out0, (const unsigned*)gath, perm, base_, hist,
                     (float2*)psum4, (float2*)pmax4);
  hipLaunchKernelGGL(k_final, dim3(128), dim3(128), 0, stream,
                     psum4, pmax4, gamma, beta, out1, out2);
}

// Round 5
// 652.689 us; speedup vs baseline: 1.4062x; 1.3954x over previous
//
#include <hip/hip_runtime.h>
#include <stdint.h>

#define MAX_DEG   10
#define DEG_COUNT 30000
#define N_ATOMS   330000      // 11 * 30000
#define NF        128
#define BATCH     128
#define SORT_BLOCKS 256

typedef __attribute__((ext_vector_type(8))) short bf16x8;   // 8 bf16 (4 VGPRs)
typedef __attribute__((ext_vector_type(4))) float f32x4;

__device__ __forceinline__ float bf2f(unsigned short h) {
  union { unsigned u; float f; } v; v.u = ((unsigned)h) << 16; return v.f;
}
__device__ __forceinline__ unsigned short f2bf(float f) {
  union { float f; unsigned u; } v; v.f = f;
  unsigned u = v.u;
  unsigned r = (u + 0x7fffu + ((u >> 16) & 1u)) >> 16;   // RNE
  return (unsigned short)r;
}

struct AdjPtrs { const int* p[10]; };

#define NEG_INF_BITS 0xFF800000

// ---------------------------------------------------------------------------
// K0: cast fp32 atoms -> bf16 copy (GEMM A-source + gather source, L3-resident)
// ---------------------------------------------------------------------------
__global__ __launch_bounds__(256) void k_cast(const float4* __restrict__ src,
                                              ushort4* __restrict__ dst) {
  size_t i = (size_t)blockIdx.x * 256 + threadIdx.x;   // one float4 -> ushort4
  float4 v = src[i];
  ushort4 o;
  o.x = f2bf(v.x); o.y = f2bf(v.y); o.z = f2bf(v.z); o.w = f2bf(v.w);
  dst[i] = o;
}

// ---------------------------------------------------------------------------
// K1a: build BcatT[d][n][k] (bf16), n,k in [0,256), from fp32 W.
// Virtual B[d][k][n]: k<128 -> neigh (Wrel | 0), k>=128 -> self (Wself | Wg)
// ---------------------------------------------------------------------------
__global__ __launch_bounds__(256) void k_build_b(const float* __restrict__ W,
                                                 unsigned short* __restrict__ BcatT) {
  int idx = blockIdx.x * 256 + threadIdx.x;
  if (idx >= 11 * 256 * 256) return;
  int d = idx >> 16;
  int rem = idx & 65535;
  int n = rem >> 8;
  int k = rem & 255;
  float v = 0.f;
  if (k < 128) {
    if (n < 128 && d >= 1) v = W[(2 * (d - 1)) * 16384 + k * 128 + n];
  } else {
    int ks = k - 128;
    if (n < 128) { int wi = (d >= 1) ? (2 * d - 1) : 20; v = W[wi * 16384 + ks * 128 + n]; }
    else         { int wi = (d >= 1) ? (20 + d)   : 31; v = W[wi * 16384 + ks * 128 + (n - 128)]; }
  }
  BcatT[idx] = f2bf(v);   // idx == d*65536 + n*256 + k
}

// K1b: biascat[d][n] f32: n<128 -> b_rel + b_self (activated), n>=128 -> b_gather
__global__ __launch_bounds__(256) void k_build_bias(const float* __restrict__ b,
                                                    float* __restrict__ biascat) {
  int idx = blockIdx.x * 256 + threadIdx.x;
  if (idx >= 11 * 256) return;
  int d = idx >> 8, n = idx & 255;
  float f;
  if (n < 128) {
    if (d >= 1) f = b[(2 * (d - 1)) * 128 + n] + b[(2 * d - 1) * 128 + n];
    else        f = b[20 * 128 + n];
  } else {
    int j = n - 128;
    f = (d >= 1) ? b[(20 + d) * 128 + j] : b[31 * 128 + j];
  }
  biascat[idx] = f;
}

// ---------------------------------------------------------------------------
// K2: neighbor sums from bf16 atom copy. One wave per atom row; lane = 2 cols.
// deg-0 rows written as zeros (B zero-block makes them inert).
// ---------------------------------------------------------------------------
__global__ __launch_bounds__(256) void k_nsum(const unsigned* __restrict__ atomsU,
                                              AdjPtrs adj,
                                              unsigned* __restrict__ nsumU) {
  int wave = threadIdx.x >> 6;
  int lane = threadIdx.x & 63;
  int row = blockIdx.x * 4 + wave;
  if (row >= N_ATOMS) return;
  int d = row / DEG_COUNT;
  if (d == 0) { nsumU[row * 64 + lane] = 0u; return; }
  int r = row - d * DEG_COUNT;
  const int* a = adj.p[d - 1];
  float s0 = 0.f, s1 = 0.f;
  for (int j = 0; j < d; ++j) {
    int nbr = a[r * d + j];
    unsigned x = atomsU[nbr * 64 + lane];
    s0 += bf2f((unsigned short)(x & 0xffff));
    s1 += bf2f((unsigned short)(x >> 16));
  }
  nsumU[row * 64 + lane] = (unsigned)f2bf(s0) | ((unsigned)f2bf(s1) << 16);
}

// ---------------------------------------------------------------------------
// K3: barrier-free streaming MFMA GEMM (unchanged from round 2).
// ---------------------------------------------------------------------------
__global__ __launch_bounds__(512, 2) void k_gemm(
    const unsigned short* __restrict__ atomsBf,
    const unsigned short* __restrict__ nsum,
    const unsigned short* __restrict__ BcatT,    // [11][256][256] n-major
    const float* __restrict__ biascat,           // [11][256]
    const float* __restrict__ gamma,
    const float* __restrict__ beta,
    float* __restrict__ out0,                    // xn FINAL (fp32)
    unsigned short* __restrict__ gath)           // gathered ws (bf16)
{
  const int d = blockIdx.y;
  const int rowTile = blockIdx.x;
  const int tid = threadIdx.x;
  const int lane = tid & 63;
  const int wave = tid >> 6;          // 0..7
  const int m16 = lane & 15;
  const int g = lane >> 4;            // k-group 0..3

  __shared__ unsigned short Bs[256 * 256];   // 128 KiB, swizzled rows of 512B

  const unsigned short* Bd = BcatT + d * 65536;

  // ---- stage B: 512 threads x 16 x 16B = 128KB, swizzled dest ----
#pragma unroll
  for (int it = 0; it < 16; ++it) {
    int flat = it * 512 + tid;        // chunk of 16B; 32 chunks per row
    int row = flat >> 5;
    int c = flat & 31;
    uint4 v = *(const uint4*)(Bd + row * 256 + c * 8);
    int kb = (c * 16) ^ ((row & 7) << 4);
    *(uint4*)((char*)Bs + row * 512 + kb) = v;
  }

  // ---- hoist A-frag loads for both 16-row chunks (hide under barrier) ----
  const int rowBase0 = rowTile * 256 + wave * 32;
  bf16x8 af0[8], af1[8];
  {
    int rbL = rowBase0 + m16; if (rbL > DEG_COUNT - 1) rbL = DEG_COUNT - 1;
    size_t gr = (size_t)d * DEG_COUNT + rbL;
#pragma unroll
    for (int ks = 0; ks < 4; ++ks)
      af0[ks] = *(const bf16x8*)(nsum + gr * 128 + ks * 32 + g * 8);
#pragma unroll
    for (int ks = 4; ks < 8; ++ks)
      af0[ks] = *(const bf16x8*)(atomsBf + gr * 128 + (ks - 4) * 32 + g * 8);
  }
  {
    int rbL = rowBase0 + 16 + m16; if (rbL > DEG_COUNT - 1) rbL = DEG_COUNT - 1;
    size_t gr = (size_t)d * DEG_COUNT + rbL;
#pragma unroll
    for (int ks = 0; ks < 4; ++ks)
      af1[ks] = *(const bf16x8*)(nsum + gr * 128 + ks * 32 + g * 8);
#pragma unroll
    for (int ks = 4; ks < 8; ++ks)
      af1[ks] = *(const bf16x8*)(atomsBf + gr * 128 + (ks - 4) * 32 + g * 8);
  }

  // ---- per-lane column constants ----
  float bias_[16], gam[8], bet[8];
#pragma unroll
  for (int ct = 0; ct < 16; ++ct) bias_[ct] = biascat[d * 256 + ct * 16 + m16];
#pragma unroll
  for (int ct = 0; ct < 8; ++ct) {
    gam[ct] = gamma[ct * 16 + m16];
    bet[ct] = beta[ct * 16 + m16];
  }

  __syncthreads();   // the only block-wide barrier

  const int ldsMask = (m16 & 7) << 4;

#pragma unroll
  for (int sub = 0; sub < 2; ++sub) {
    const int rowBase = rowBase0 + sub * 16;
    f32x4 acc[16];
#pragma unroll
    for (int ct = 0; ct < 16; ++ct) acc[ct] = (f32x4){0.f, 0.f, 0.f, 0.f};

#pragma unroll
    for (int ct = 0; ct < 16; ++ct) {
      const char* bbase = (const char*)Bs + (ct * 16 + m16) * 512;
      bf16x8 bf[8];
#pragma unroll
      for (int ks = 0; ks < 8; ++ks)
        bf[ks] = *(const bf16x8*)(bbase + ((ks * 64 + g * 16) ^ ldsMask));
#pragma unroll
      for (int ks = 0; ks < 8; ++ks) {
        bf16x8 a = (sub == 0) ? af0[ks] : af1[ks];
        acc[ct] = __builtin_amdgcn_mfma_f32_16x16x32_bf16(a, bf[ks], acc[ct], 0, 0, 0);
      }
    }

    // ---- epilogue: bias, LN over cols 0..127, stores (no barriers) ----
#pragma unroll
    for (int ct = 0; ct < 16; ++ct)
#pragma unroll
      for (int r = 0; r < 4; ++r) acc[ct][r] += bias_[ct];

    float s[4], qq[4];
#pragma unroll
    for (int r = 0; r < 4; ++r) {
      s[r] = 0.f; qq[r] = 0.f;
#pragma unroll
      for (int ct = 0; ct < 8; ++ct) {
        float v = acc[ct][r];
        s[r] += v; qq[r] += v * v;
      }
    }
#pragma unroll
    for (int off = 8; off >= 1; off >>= 1) {
#pragma unroll
      for (int r = 0; r < 4; ++r) {
        s[r]  += __shfl_xor(s[r],  off, 64);
        qq[r] += __shfl_xor(qq[r], off, 64);
      }
    }

#pragma unroll
    for (int r = 0; r < 4; ++r) {
      int rb = rowBase + g * 4 + r;
      float mean = s[r] * (1.0f / 128.0f);
      float var  = qq[r] * (1.0f / 128.0f) - mean * mean;
      float inv  = 1.0f / (sqrtf(var + 1e-5f) + 1e-5f);   // ref: sqrt(var+eps)+eps
      if (rb < DEG_COUNT) {
        size_t grow = (size_t)d * DEG_COUNT + rb;
#pragma unroll
        for (int ct = 0; ct < 8; ++ct)
          out0[grow * 128 + ct * 16 + m16] = gam[ct] * ((acc[ct][r] - mean) * inv) + bet[ct];
#pragma unroll
        for (int ct = 8; ct < 16; ++ct)
          gath[grow * 128 + (ct - 8) * 16 + m16] = f2bf(acc[ct][r]);
      }
    }
  }
}

// ---------------------------------------------------------------------------
// Counting sort by membership — atomic-contention-free 3-phase version.
// (Round-4 k_scatter: 330K global atomicAdd over 128 words = 265us of pure
// contention. Now: per-block LDS histograms -> tiny scan -> block-local
// LDS-offset scatter. Zero global atomics.)
// ---------------------------------------------------------------------------
__global__ __launch_bounds__(256) void k_hist2(const int* __restrict__ membership,
                                               int* __restrict__ blockHist) {
  __shared__ int bins[BATCH];
  int tid = threadIdx.x;
  if (tid < BATCH) bins[tid] = 0;
  __syncthreads();
  const int chunk = (N_ATOMS + SORT_BLOCKS - 1) / SORT_BLOCKS;
  int lo = blockIdx.x * chunk, hi = min(lo + chunk, N_ATOMS);
  for (int i = lo + tid; i < hi; i += 256)
    atomicAdd(&bins[membership[i]], 1);
  __syncthreads();
  if (tid < BATCH) blockHist[blockIdx.x * BATCH + tid] = bins[tid];
}

// 1 block, 128 threads: thread m = bin m. Column-sum, exclusive bin scan,
// then per-block running offsets off[b][m].
__global__ __launch_bounds__(128) void k_scan2(const int* __restrict__ blockHist,
                                               int* __restrict__ off,     // [SORT_BLOCKS][128]
                                               int* __restrict__ base,
                                               int* __restrict__ hist) {
  int m = threadIdx.x;
  int tot = 0;
  for (int b = 0; b < SORT_BLOCKS; ++b) tot += blockHist[b * BATCH + m];
  hist[m] = tot;
  __shared__ int t[BATCH];
  t[m] = tot;
  __syncthreads();
  int acc = 0;
  for (int i = 0; i < m; ++i) acc += t[i];   // 128 LDS reads max — trivial
  base[m] = acc;
  int run = acc;
  for (int b = 0; b < SORT_BLOCKS; ++b) {
    off[b * BATCH + m] = run;
    run += blockHist[b * BATCH + m];
  }
}

// Per-block scatter: seed LDS bins with this block's global offsets, then
// block-local LDS int atomics (<=1.3K/block) + plain 4B global writes.
__global__ __launch_bounds__(256) void k_scatter2(const int* __restrict__ membership,
                                                  const int* __restrict__ off,
                                                  int* __restrict__ perm) {
  __shared__ int bins[BATCH];
  int tid = threadIdx.x;
  if (tid < BATCH) bins[tid] = off[blockIdx.x * BATCH + tid];
  __syncthreads();
  const int chunk = (N_ATOMS + SORT_BLOCKS - 1) / SORT_BLOCKS;
  int lo = blockIdx.x * chunk, hi = min(lo + chunk, N_ATOMS);
  for (int i = lo + tid; i < hi; i += 256) {
    int m = membership[i];
    int pos = atomicAdd(&bins[m], 1);
    perm[pos] = i;
  }
}

// ---------------------------------------------------------------------------
// K_reduce: fused segment-max(xn) + segment-sum(gath), atomic-free.
// 512 blocks = 128 molecules x 4 slices; 8 waves stride the slice's perm
// range; whole-row gathers (coalesced 512B/256B); register accumulation;
// LDS cross-wave reduce; writes tiny per-slice partials.
// ---------------------------------------------------------------------------
__global__ __launch_bounds__(512) void k_reduce(
    const float2* __restrict__ xnV,         // out0 as float2
    const unsigned* __restrict__ gathU,
    const int* __restrict__ perm,
    const int* __restrict__ base,
    const int* __restrict__ hist,
    float2* __restrict__ psum4,             // [4][128][64] float2
    float2* __restrict__ pmax4)             // [4][128][64] float2
{
  const int m = blockIdx.x >> 2;
  const int s = blockIdx.x & 3;
  const int b0 = base[m], cnt = hist[m];
  const int lo = b0 + (cnt * s) / 4;
  const int hi = b0 + (cnt * (s + 1)) / 4;
  const int wave = threadIdx.x >> 6, lane = threadIdx.x & 63;

  const float NEG_INF = __int_as_float((int)NEG_INF_BITS);
  float mx0 = NEG_INF, mx1 = NEG_INF, s0 = 0.f, s1 = 0.f;

#pragma unroll 4
  for (int i = lo + wave; i < hi; i += 8) {
    int r = perm[i];
    float2 x = xnV[(size_t)r * 64 + lane];
    unsigned gg = gathU[(size_t)r * 64 + lane];
    mx0 = fmaxf(mx0, x.x);
    mx1 = fmaxf(mx1, x.y);
    s0 += bf2f((unsigned short)(gg & 0xffff));
    s1 += bf2f((unsigned short)(gg >> 16));
  }

  __shared__ float2 sumT[8][64];
  __shared__ float2 maxT[8][64];
  sumT[wave][lane] = make_float2(s0, s1);
  maxT[wave][lane] = make_float2(mx0, mx1);
  __syncthreads();

  if (threadIdx.x < 64) {
    int l = threadIdx.x;
    float2 ss = sumT[0][l];
    float2 mm = maxT[0][l];
#pragma unroll
    for (int w = 1; w < 8; ++w) {
      float2 a = sumT[w][l]; ss.x += a.x; ss.y += a.y;
      float2 b = maxT[w][l]; mm.x = fmaxf(mm.x, b.x); mm.y = fmaxf(mm.y, b.y);
    }
    psum4[(s * 128 + m) * 64 + l] = ss;
    pmax4[(s * 128 + m) * 64 + l] = mm;
  }
}

// K6: merge 4 slices; norm sum -> yn (out1); max -> g (out2). fp32.
__global__ __launch_bounds__(128) void k_final(
    const float* __restrict__ psum4,        // [4][128][128]
    const float* __restrict__ pmax4,
    const float* __restrict__ gamma,
    const float* __restrict__ beta,
    float* __restrict__ out1,
    float* __restrict__ out2)
{
  int m = blockIdx.x;
  int j = threadIdx.x;
  float s = 0.f, g = __int_as_float((int)NEG_INF_BITS);
#pragma unroll
  for (int sl = 0; sl < 4; ++sl) {
    s += psum4[(sl * 128 + m) * 128 + j];
    g = fmaxf(g, pmax4[(sl * 128 + m) * 128 + j]);
  }
  out2[m * 128 + j] = g;

  float ws_ = s, wq = s * s;
#pragma unroll
  for (int off = 32; off >= 1; off >>= 1) {
    ws_ += __shfl_xor(ws_, off, 64);
    wq  += __shfl_xor(wq, off, 64);
  }
  __shared__ float red[4];
  int wave = j >> 6, lane = j & 63;
  if (lane == 0) { red[wave * 2] = ws_; red[wave * 2 + 1] = wq; }
  __syncthreads();
  float S = red[0] + red[2], Q = red[1] + red[3];
  float mean = S * (1.f / 128.f);
  float var = Q * (1.f / 128.f) - mean * mean;
  float inv = 1.f / (sqrtf(var + 1e-5f) + 1e-5f);
  float yn = gamma[j] * ((s - mean) * inv) + beta[j];
  out1[m * 128 + j] = yn;
}

// ---------------------------------------------------------------------------
extern "C" void kernel_launch(void* const* d_in, const int* in_sizes, int n_in,
                              void* d_out, int out_size, void* d_ws, size_t ws_size,
                              hipStream_t stream) {
  const float* atoms = (const float*)d_in[0];
  // d_in[1] = deg_slice (unused; buckets are static)
  const int* membership = (const int*)d_in[2];
  AdjPtrs adj;
  for (int i = 0; i < 10; ++i) adj.p[i] = (const int*)d_in[3 + i];
  const float* W     = (const float*)d_in[13];
  const float* b     = (const float*)d_in[14];
  const float* gamma = (const float*)d_in[15];
  const float* beta  = (const float*)d_in[16];

  char* ws = (char*)d_ws;
  size_t off = 0;
  unsigned short* atomsBf = (unsigned short*)(ws + off); off += (size_t)N_ATOMS * 128 * 2;
  unsigned short* nsum    = (unsigned short*)(ws + off); off += (size_t)N_ATOMS * 128 * 2;
  unsigned short* gath    = (unsigned short*)(ws + off); off += (size_t)N_ATOMS * 128 * 2;
  unsigned short* BcatT   = (unsigned short*)(ws + off); off += (size_t)11 * 256 * 256 * 2;
  float* biascat          = (float*)(ws + off);          off += (size_t)11 * 256 * 4;

  // Sort + reduction scratch reuses atomsBf's space (dead after k_gemm):
  char* scr = (char*)atomsBf;
  int* perm      = (int*)(scr);                          // 1.32 MB
  int* hist      = (int*)(scr + 2 * 1024 * 1024);        // 512 B
  int* base_     = (int*)(scr + 2 * 1024 * 1024 + 1024);
  int* blockHist = (int*)(scr + 2 * 1024 * 1024 + 4096); // 128 KB
  int* offTab    = (int*)(scr + 2 * 1024 * 1024 + 4096 + SORT_BLOCKS * BATCH * 4); // 128 KB
  float* psum4   = (float*)(scr + 3 * 1024 * 1024);      // 256 KB
  float* pmax4   = (float*)(scr + 3 * 1024 * 1024 + 256 * 1024);

  float* out0 = (float*)d_out;
  float* out1 = out0 + (size_t)N_ATOMS * 128;
  float* out2 = out1 + 16384;

  hipLaunchKernelGGL(k_cast, dim3(N_ATOMS * 128 / 4 / 256), dim3(256), 0, stream,
                     (const float4*)atoms, (ushort4*)atomsBf);
  hipLaunchKernelGGL(k_build_b, dim3((11 * 256 * 256 + 255) / 256), dim3(256), 0, stream, W, BcatT);
  hipLaunchKernelGGL(k_build_bias, dim3((11 * 256 + 255) / 256), dim3(256), 0, stream, b, biascat);
  hipLaunchKernelGGL(k_nsum, dim3(N_ATOMS / 4), dim3(256), 0, stream,
                     (const unsigned*)atomsBf, adj, (unsigned*)nsum);
  hipLaunchKernelGGL(k_gemm, dim3(118, 11), dim3(512), 0, stream,
                     atomsBf, nsum, BcatT, biascat, gamma, beta, out0, gath);
  // counting sort (scratch overlays dead atomsBf; zero global atomics)
  hipLaunchKernelGGL(k_hist2, dim3(SORT_BLOCKS), dim3(256), 0, stream, membership, blockHist);
  hipLaunchKernelGGL(k_scan2, dim3(1), dim3(128), 0, stream, blockHist, offTab, base_, hist);
  hipLaunchKernelGGL(k_scatter2, dim3(SORT_BLOCKS), dim3(256), 0, stream, membership, offTab, perm);
  // fused atomic-free segment max + sum
  hipLaunchKernelGGL(k_reduce, dim3(512), dim3(512), 0, stream,
                     (const float2*)out0, (const unsigned*)gath, perm, base_, hist,
                     (float2*)psum4, (float2*)pmax4);
  hipLaunchKernelGGL(k_final, dim3(128), dim3(128), 0, stream,
                     psum4, pmax4, gamma, beta, out1, out2);
}

// Round 6
// 563.603 us; speedup vs baseline: 1.6285x; 1.1581x over previous
//
#include <hip/hip_runtime.h>
#include <stdint.h>

#define MAX_DEG   10
#define DEG_COUNT 30000
#define N_ATOMS   330000      // 11 * 30000
#define NF        128
#define BATCH     128
#define SORT_BLOCKS 256

typedef __attribute__((ext_vector_type(8))) short bf16x8;   // 8 bf16 (4 VGPRs)
typedef __attribute__((ext_vector_type(4))) float f32x4;

__device__ __forceinline__ float bf2f(unsigned short h) {
  union { unsigned u; float f; } v; v.u = ((unsigned)h) << 16; return v.f;
}
__device__ __forceinline__ unsigned short f2bf(float f) {
  union { float f; unsigned u; } v; v.f = f;
  unsigned u = v.u;
  unsigned r = (u + 0x7fffu + ((u >> 16) & 1u)) >> 16;   // RNE
  return (unsigned short)r;
}

struct AdjPtrs { const int* p[10]; };

#define NEG_INF_BITS 0xFF800000

// ---------------------------------------------------------------------------
// K0: cast fp32 atoms -> bf16 copy (GEMM A-source + gather source, L3-resident)
// ---------------------------------------------------------------------------
__global__ __launch_bounds__(256) void k_cast(const float4* __restrict__ src,
                                              ushort4* __restrict__ dst) {
  size_t i = (size_t)blockIdx.x * 256 + threadIdx.x;   // one float4 -> ushort4
  float4 v = src[i];
  ushort4 o;
  o.x = f2bf(v.x); o.y = f2bf(v.y); o.z = f2bf(v.z); o.w = f2bf(v.w);
  dst[i] = o;
}

// ---------------------------------------------------------------------------
// K1a: build BcatT[d][n][k] (bf16), n,k in [0,256), from fp32 W.
// Virtual B[d][k][n]: k<128 -> neigh (Wrel | 0), k>=128 -> self (Wself | Wg)
// ---------------------------------------------------------------------------
__global__ __launch_bounds__(256) void k_build_b(const float* __restrict__ W,
                                                 unsigned short* __restrict__ BcatT) {
  int idx = blockIdx.x * 256 + threadIdx.x;
  if (idx >= 11 * 256 * 256) return;
  int d = idx >> 16;
  int rem = idx & 65535;
  int n = rem >> 8;
  int k = rem & 255;
  float v = 0.f;
  if (k < 128) {
    if (n < 128 && d >= 1) v = W[(2 * (d - 1)) * 16384 + k * 128 + n];
  } else {
    int ks = k - 128;
    if (n < 128) { int wi = (d >= 1) ? (2 * d - 1) : 20; v = W[wi * 16384 + ks * 128 + n]; }
    else         { int wi = (d >= 1) ? (20 + d)   : 31; v = W[wi * 16384 + ks * 128 + (n - 128)]; }
  }
  BcatT[idx] = f2bf(v);   // idx == d*65536 + n*256 + k
}

// K1b: biascat[d][n] f32: n<128 -> b_rel + b_self (activated), n>=128 -> b_gather
__global__ __launch_bounds__(256) void k_build_bias(const float* __restrict__ b,
                                                    float* __restrict__ biascat) {
  int idx = blockIdx.x * 256 + threadIdx.x;
  if (idx >= 11 * 256) return;
  int d = idx >> 8, n = idx & 255;
  float f;
  if (n < 128) {
    if (d >= 1) f = b[(2 * (d - 1)) * 128 + n] + b[(2 * d - 1) * 128 + n];
    else        f = b[20 * 128 + n];
  } else {
    int j = n - 128;
    f = (d >= 1) ? b[(20 + d) * 128 + j] : b[31 * 128 + j];
  }
  biascat[idx] = f;
}

// ---------------------------------------------------------------------------
// K2: neighbor sums — MLP version. One wave = 2 consecutive rows (same degree;
// 30000 % 8 == 0 so blocks never straddle buckets). The 2D neighbor indices
// are contiguous: one coalesced lane-load + shfl broadcast; all 2D row
// gathers issue independently (unrolled) before any accumulation.
// Accumulation stays j-ascending per row => bit-identical to round 5.
// ---------------------------------------------------------------------------
template<int D>
__device__ __forceinline__ void nsum_body2(const unsigned* __restrict__ atomsU,
                                           const int* __restrict__ a,   // 2D ints
                                           int lane,
                                           unsigned* __restrict__ out) { // row0 base
  int myIdx = (lane < 2 * D) ? a[lane] : 0;
  unsigned xs[2 * D];
#pragma unroll
  for (int j = 0; j < 2 * D; ++j) {
    int nbr = __shfl(myIdx, j, 64);
    xs[j] = atomsU[(size_t)nbr * 64 + lane];
  }
  float s0a = 0.f, s1a = 0.f, s0b = 0.f, s1b = 0.f;
#pragma unroll
  for (int j = 0; j < D; ++j) {
    s0a += bf2f((unsigned short)(xs[j] & 0xffff));
    s1a += bf2f((unsigned short)(xs[j] >> 16));
  }
#pragma unroll
  for (int j = D; j < 2 * D; ++j) {
    s0b += bf2f((unsigned short)(xs[j] & 0xffff));
    s1b += bf2f((unsigned short)(xs[j] >> 16));
  }
  out[lane]      = (unsigned)f2bf(s0a) | ((unsigned)f2bf(s1a) << 16);
  out[64 + lane] = (unsigned)f2bf(s0b) | ((unsigned)f2bf(s1b) << 16);
}

__global__ __launch_bounds__(256) void k_nsum(const unsigned* __restrict__ atomsU,
                                              AdjPtrs adj,
                                              unsigned* __restrict__ nsumU) {
  int wave = threadIdx.x >> 6;
  int lane = threadIdx.x & 63;
  int row0 = blockIdx.x * 8 + wave * 2;          // 2 rows per wave
  int d = row0 / DEG_COUNT;                       // wave-uniform; both rows same d
  unsigned* out = nsumU + (size_t)row0 * 64;
  if (d == 0) { out[lane] = 0u; out[64 + lane] = 0u; return; }
  int r = row0 - d * DEG_COUNT;
  const int* a = adj.p[d - 1] + (size_t)r * d;   // rows r and r+1: a[0..2d)
  switch (d) {
    case 1:  nsum_body2<1>(atomsU, a, lane, out); break;
    case 2:  nsum_body2<2>(atomsU, a, lane, out); break;
    case 3:  nsum_body2<3>(atomsU, a, lane, out); break;
    case 4:  nsum_body2<4>(atomsU, a, lane, out); break;
    case 5:  nsum_body2<5>(atomsU, a, lane, out); break;
    case 6:  nsum_body2<6>(atomsU, a, lane, out); break;
    case 7:  nsum_body2<7>(atomsU, a, lane, out); break;
    case 8:  nsum_body2<8>(atomsU, a, lane, out); break;
    case 9:  nsum_body2<9>(atomsU, a, lane, out); break;
    default: nsum_body2<10>(atomsU, a, lane, out); break;
  }
}

// ---------------------------------------------------------------------------
// K3: barrier-free streaming MFMA GEMM (unchanged from round 2).
// ---------------------------------------------------------------------------
__global__ __launch_bounds__(512, 2) void k_gemm(
    const unsigned short* __restrict__ atomsBf,
    const unsigned short* __restrict__ nsum,
    const unsigned short* __restrict__ BcatT,    // [11][256][256] n-major
    const float* __restrict__ biascat,           // [11][256]
    const float* __restrict__ gamma,
    const float* __restrict__ beta,
    float* __restrict__ out0,                    // xn FINAL (fp32)
    unsigned short* __restrict__ gath)           // gathered ws (bf16)
{
  const int d = blockIdx.y;
  const int rowTile = blockIdx.x;
  const int tid = threadIdx.x;
  const int lane = tid & 63;
  const int wave = tid >> 6;          // 0..7
  const int m16 = lane & 15;
  const int g = lane >> 4;            // k-group 0..3

  __shared__ unsigned short Bs[256 * 256];   // 128 KiB, swizzled rows of 512B

  const unsigned short* Bd = BcatT + d * 65536;

  // ---- stage B: 512 threads x 16 x 16B = 128KB, swizzled dest ----
#pragma unroll
  for (int it = 0; it < 16; ++it) {
    int flat = it * 512 + tid;        // chunk of 16B; 32 chunks per row
    int row = flat >> 5;
    int c = flat & 31;
    uint4 v = *(const uint4*)(Bd + row * 256 + c * 8);
    int kb = (c * 16) ^ ((row & 7) << 4);
    *(uint4*)((char*)Bs + row * 512 + kb) = v;
  }

  // ---- hoist A-frag loads for both 16-row chunks (hide under barrier) ----
  const int rowBase0 = rowTile * 256 + wave * 32;
  bf16x8 af0[8], af1[8];
  {
    int rbL = rowBase0 + m16; if (rbL > DEG_COUNT - 1) rbL = DEG_COUNT - 1;
    size_t gr = (size_t)d * DEG_COUNT + rbL;
#pragma unroll
    for (int ks = 0; ks < 4; ++ks)
      af0[ks] = *(const bf16x8*)(nsum + gr * 128 + ks * 32 + g * 8);
#pragma unroll
    for (int ks = 4; ks < 8; ++ks)
      af0[ks] = *(const bf16x8*)(atomsBf + gr * 128 + (ks - 4) * 32 + g * 8);
  }
  {
    int rbL = rowBase0 + 16 + m16; if (rbL > DEG_COUNT - 1) rbL = DEG_COUNT - 1;
    size_t gr = (size_t)d * DEG_COUNT + rbL;
#pragma unroll
    for (int ks = 0; ks < 4; ++ks)
      af1[ks] = *(const bf16x8*)(nsum + gr * 128 + ks * 32 + g * 8);
#pragma unroll
    for (int ks = 4; ks < 8; ++ks)
      af1[ks] = *(const bf16x8*)(atomsBf + gr * 128 + (ks - 4) * 32 + g * 8);
  }

  // ---- per-lane column constants ----
  float bias_[16], gam[8], bet[8];
#pragma unroll
  for (int ct = 0; ct < 16; ++ct) bias_[ct] = biascat[d * 256 + ct * 16 + m16];
#pragma unroll
  for (int ct = 0; ct < 8; ++ct) {
    gam[ct] = gamma[ct * 16 + m16];
    bet[ct] = beta[ct * 16 + m16];
  }

  __syncthreads();   // the only block-wide barrier

  const int ldsMask = (m16 & 7) << 4;

#pragma unroll
  for (int sub = 0; sub < 2; ++sub) {
    const int rowBase = rowBase0 + sub * 16;
    f32x4 acc[16];
#pragma unroll
    for (int ct = 0; ct < 16; ++ct) acc[ct] = (f32x4){0.f, 0.f, 0.f, 0.f};

#pragma unroll
    for (int ct = 0; ct < 16; ++ct) {
      const char* bbase = (const char*)Bs + (ct * 16 + m16) * 512;
      bf16x8 bf[8];
#pragma unroll
      for (int ks = 0; ks < 8; ++ks)
        bf[ks] = *(const bf16x8*)(bbase + ((ks * 64 + g * 16) ^ ldsMask));
#pragma unroll
      for (int ks = 0; ks < 8; ++ks) {
        bf16x8 a = (sub == 0) ? af0[ks] : af1[ks];
        acc[ct] = __builtin_amdgcn_mfma_f32_16x16x32_bf16(a, bf[ks], acc[ct], 0, 0, 0);
      }
    }

    // ---- epilogue: bias, LN over cols 0..127, stores (no barriers) ----
#pragma unroll
    for (int ct = 0; ct < 16; ++ct)
#pragma unroll
      for (int r = 0; r < 4; ++r) acc[ct][r] += bias_[ct];

    float s[4], qq[4];
#pragma unroll
    for (int r = 0; r < 4; ++r) {
      s[r] = 0.f; qq[r] = 0.f;
#pragma unroll
      for (int ct = 0; ct < 8; ++ct) {
        float v = acc[ct][r];
        s[r] += v; qq[r] += v * v;
      }
    }
#pragma unroll
    for (int off = 8; off >= 1; off >>= 1) {
#pragma unroll
      for (int r = 0; r < 4; ++r) {
        s[r]  += __shfl_xor(s[r],  off, 64);
        qq[r] += __shfl_xor(qq[r], off, 64);
      }
    }

#pragma unroll
    for (int r = 0; r < 4; ++r) {
      int rb = rowBase + g * 4 + r;
      float mean = s[r] * (1.0f / 128.0f);
      float var  = qq[r] * (1.0f / 128.0f) - mean * mean;
      float inv  = 1.0f / (sqrtf(var + 1e-5f) + 1e-5f);   // ref: sqrt(var+eps)+eps
      if (rb < DEG_COUNT) {
        size_t grow = (size_t)d * DEG_COUNT + rb;
#pragma unroll
        for (int ct = 0; ct < 8; ++ct)
          out0[grow * 128 + ct * 16 + m16] = gam[ct] * ((acc[ct][r] - mean) * inv) + bet[ct];
#pragma unroll
        for (int ct = 8; ct < 16; ++ct)
          gath[grow * 128 + (ct - 8) * 16 + m16] = f2bf(acc[ct][r]);
      }
    }
  }
}

// ---------------------------------------------------------------------------
// Counting sort by membership — atomic-contention-free 3-phase version.
// ---------------------------------------------------------------------------
__global__ __launch_bounds__(256) void k_hist2(const int* __restrict__ membership,
                                               int* __restrict__ blockHist) {
  __shared__ int bins[BATCH];
  int tid = threadIdx.x;
  if (tid < BATCH) bins[tid] = 0;
  __syncthreads();
  const int chunk = (N_ATOMS + SORT_BLOCKS - 1) / SORT_BLOCKS;
  int lo = blockIdx.x * chunk, hi = min(lo + chunk, N_ATOMS);
  for (int i = lo + tid; i < hi; i += 256)
    atomicAdd(&bins[membership[i]], 1);
  __syncthreads();
  if (tid < BATCH) blockHist[blockIdx.x * BATCH + tid] = bins[tid];
}

// 1 block, 128 threads: thread m = bin m. Column-sum, exclusive bin scan,
// then per-block running offsets off[b][m].
__global__ __launch_bounds__(128) void k_scan2(const int* __restrict__ blockHist,
                                               int* __restrict__ off,     // [SORT_BLOCKS][128]
                                               int* __restrict__ base,
                                               int* __restrict__ hist) {
  int m = threadIdx.x;
  int tot = 0;
  for (int b = 0; b < SORT_BLOCKS; ++b) tot += blockHist[b * BATCH + m];
  hist[m] = tot;
  __shared__ int t[BATCH];
  t[m] = tot;
  __syncthreads();
  int acc = 0;
  for (int i = 0; i < m; ++i) acc += t[i];   // 128 LDS reads max — trivial
  base[m] = acc;
  int run = acc;
  for (int b = 0; b < SORT_BLOCKS; ++b) {
    off[b * BATCH + m] = run;
    run += blockHist[b * BATCH + m];
  }
}

// Per-block scatter: seed LDS bins with this block's global offsets, then
// block-local LDS int atomics (<=1.3K/block) + plain 4B global writes.
__global__ __launch_bounds__(256) void k_scatter2(const int* __restrict__ membership,
                                                  const int* __restrict__ off,
                                                  int* __restrict__ perm) {
  __shared__ int bins[BATCH];
  int tid = threadIdx.x;
  if (tid < BATCH) bins[tid] = off[blockIdx.x * BATCH + tid];
  __syncthreads();
  const int chunk = (N_ATOMS + SORT_BLOCKS - 1) / SORT_BLOCKS;
  int lo = blockIdx.x * chunk, hi = min(lo + chunk, N_ATOMS);
  for (int i = lo + tid; i < hi; i += 256) {
    int m = membership[i];
    int pos = atomicAdd(&bins[m], 1);
    perm[pos] = i;
  }
}

// ---------------------------------------------------------------------------
// K_reduce: fused segment-max(xn) + segment-sum(gath), atomic-free.
// ---------------------------------------------------------------------------
__global__ __launch_bounds__(512) void k_reduce(
    const float2* __restrict__ xnV,         // out0 as float2
    const unsigned* __restrict__ gathU,
    const int* __restrict__ perm,
    const int* __restrict__ base,
    const int* __restrict__ hist,
    float2* __restrict__ psum4,             // [4][128][64] float2
    float2* __restrict__ pmax4)             // [4][128][64] float2
{
  const int m = blockIdx.x >> 2;
  const int s = blockIdx.x & 3;
  const int b0 = base[m], cnt = hist[m];
  const int lo = b0 + (cnt * s) / 4;
  const int hi = b0 + (cnt * (s + 1)) / 4;
  const int wave = threadIdx.x >> 6, lane = threadIdx.x & 63;

  const float NEG_INF = __int_as_float((int)NEG_INF_BITS);
  float mx0 = NEG_INF, mx1 = NEG_INF, s0 = 0.f, s1 = 0.f;

#pragma unroll 4
  for (int i = lo + wave; i < hi; i += 8) {
    int r = perm[i];
    float2 x = xnV[(size_t)r * 64 + lane];
    unsigned gg = gathU[(size_t)r * 64 + lane];
    mx0 = fmaxf(mx0, x.x);
    mx1 = fmaxf(mx1, x.y);
    s0 += bf2f((unsigned short)(gg & 0xffff));
    s1 += bf2f((unsigned short)(gg >> 16));
  }

  __shared__ float2 sumT[8][64];
  __shared__ float2 maxT[8][64];
  sumT[wave][lane] = make_float2(s0, s1);
  maxT[wave][lane] = make_float2(mx0, mx1);
  __syncthreads();

  if (threadIdx.x < 64) {
    int l = threadIdx.x;
    float2 ss = sumT[0][l];
    float2 mm = maxT[0][l];
#pragma unroll
    for (int w = 1; w < 8; ++w) {
      float2 a = sumT[w][l]; ss.x += a.x; ss.y += a.y;
      float2 b = maxT[w][l]; mm.x = fmaxf(mm.x, b.x); mm.y = fmaxf(mm.y, b.y);
    }
    psum4[(s * 128 + m) * 64 + l] = ss;
    pmax4[(s * 128 + m) * 64 + l] = mm;
  }
}

// K6: merge 4 slices; norm sum -> yn (out1); max -> g (out2). fp32.
__global__ __launch_bounds__(128) void k_final(
    const float* __restrict__ psum4,        // [4][128][128]
    const float* __restrict__ pmax4,
    const float* __restrict__ gamma,
    const float* __restrict__ beta,
    float* __restrict__ out1,
    float* __restrict__ out2)
{
  int m = blockIdx.x;
  int j = threadIdx.x;
  float s = 0.f, g = __int_as_float((int)NEG_INF_BITS);
#pragma unroll
  for (int sl = 0; sl < 4; ++sl) {
    s += psum4[(sl * 128 + m) * 128 + j];
    g = fmaxf(g, pmax4[(sl * 128 + m) * 128 + j]);
  }
  out2[m * 128 + j] = g;

  float ws_ = s, wq = s * s;
#pragma unroll
  for (int off = 32; off >= 1; off >>= 1) {
    ws_ += __shfl_xor(ws_, off, 64);
    wq  += __shfl_xor(wq, off, 64);
  }
  __shared__ float red[4];
  int wave = j >> 6, lane = j & 63;
  if (lane == 0) { red[wave * 2] = ws_; red[wave * 2 + 1] = wq; }
  __syncthreads();
  float S = red[0] + red[2], Q = red[1] + red[3];
  float mean = S * (1.f / 128.f);
  float var = Q * (1.f / 128.f) - mean * mean;
  float inv = 1.f / (sqrtf(var + 1e-5f) + 1e-5f);
  float yn = gamma[j] * ((s - mean) * inv) + beta[j];
  out1[m * 128 + j] = yn;
}

// ---------------------------------------------------------------------------
extern "C" void kernel_launch(void* const* d_in, const int* in_sizes, int n_in,
                              void* d_out, int out_size, void* d_ws, size_t ws_size,
                              hipStream_t stream) {
  const float* atoms = (const float*)d_in[0];
  // d_in[1] = deg_slice (unused; buckets are static)
  const int* membership = (const int*)d_in[2];
  AdjPtrs adj;
  for (int i = 0; i < 10; ++i) adj.p[i] = (const int*)d_in[3 + i];
  const float* W     = (const float*)d_in[13];
  const float* b     = (const float*)d_in[14];
  const float* gamma = (const float*)d_in[15];
  const float* beta  = (const float*)d_in[16];

  char* ws = (char*)d_ws;
  size_t off = 0;
  unsigned short* atomsBf = (unsigned short*)(ws + off); off += (size_t)N_ATOMS * 128 * 2;
  unsigned short* nsum    = (unsigned short*)(ws + off); off += (size_t)N_ATOMS * 128 * 2;
  unsigned short* gath    = (unsigned short*)(ws + off); off += (size_t)N_ATOMS * 128 * 2;
  unsigned short* BcatT   = (unsigned short*)(ws + off); off += (size_t)11 * 256 * 256 * 2;
  float* biascat          = (float*)(ws + off);          off += (size_t)11 * 256 * 4;

  // Sort + reduction scratch reuses atomsBf's space (dead after k_gemm):
  char* scr = (char*)atomsBf;
  int* perm      = (int*)(scr);                          // 1.32 MB
  int* hist      = (int*)(scr + 2 * 1024 * 1024);        // 512 B
  int* base_     = (int*)(scr + 2 * 1024 * 1024 + 1024);
  int* blockHist = (int*)(scr + 2 * 1024 * 1024 + 4096); // 128 KB
  int* offTab    = (int*)(scr + 2 * 1024 * 1024 + 4096 + SORT_BLOCKS * BATCH * 4); // 128 KB
  float* psum4   = (float*)(scr + 3 * 1024 * 1024);      // 256 KB
  float* pmax4   = (float*)(scr + 3 * 1024 * 1024 + 256 * 1024);

  float* out0 = (float*)d_out;
  float* out1 = out0 + (size_t)N_ATOMS * 128;
  float* out2 = out1 + 16384;

  hipLaunchKernelGGL(k_cast, dim3(N_ATOMS * 128 / 4 / 256), dim3(256), 0, stream,
                     (const float4*)atoms, (ushort4*)atomsBf);
  hipLaunchKernelGGL(k_build_b, dim3((11 * 256 * 256 + 255) / 256), dim3(256), 0, stream, W, BcatT);
  hipLaunchKernelGGL(k_build_bias, dim3((11 * 256 + 255) / 256), dim3(256), 0, stream, b, biascat);
  hipLaunchKernelGGL(k_nsum, dim3(N_ATOMS / 8), dim3(256), 0, stream,
                     (const unsigned*)atomsBf, adj, (unsigned*)nsum);
  hipLaunchKernelGGL(k_gemm, dim3(118, 11), dim3(512), 0, stream,
                     atomsBf, nsum, BcatT, biascat, gamma, beta, out0, gath);
  // counting sort (scratch overlays dead atomsBf; zero global atomics)
  hipLaunchKernelGGL(k_hist2, dim3(SORT_BLOCKS), dim3(256), 0, stream, membership, blockHist);
  hipLaunchKernelGGL(k_scan2, dim3(1), dim3(128), 0, stream, blockHist, offTab, base_, hist);
  hipLaunchKernelGGL(k_scatter2, dim3(SORT_BLOCKS), dim3(256), 0, stream, membership, offTab, perm);
  // fused atomic-free segment max + sum
  hipLaunchKernelGGL(k_reduce, dim3(512), dim3(512), 0, stream,
                     (const float2*)out0, (const unsigned*)gath, perm, base_, hist,
                     (float2*)psum4, (float2*)pmax4);
  hipLaunchKernelGGL(k_final, dim3(128), dim3(128), 0, stream,
                     psum4, pmax4, gamma, beta, out1, out2);
}

// Round 7
// 561.189 us; speedup vs baseline: 1.6355x; 1.0043x over previous
//
#include <hip/hip_runtime.h>
#include <stdint.h>

#define MAX_DEG   10
#define DEG_COUNT 30000
#define N_ATOMS   330000      // 11 * 30000
#define NF        128
#define BATCH     128
#define SORT_BLOCKS 256

typedef __attribute__((ext_vector_type(8))) short bf16x8;   // 8 bf16 (4 VGPRs)
typedef __attribute__((ext_vector_type(4))) float f32x4;

__device__ __forceinline__ float bf2f(unsigned short h) {
  union { unsigned u; float f; } v; v.u = ((unsigned)h) << 16; return v.f;
}
__device__ __forceinline__ unsigned short f2bf(float f) {
  union { float f; unsigned u; } v; v.f = f;
  unsigned u = v.u;
  unsigned r = (u + 0x7fffu + ((u >> 16) & 1u)) >> 16;   // RNE
  return (unsigned short)r;
}

struct AdjPtrs { const int* p[10]; };

#define NEG_INF_BITS 0xFF800000

// ---------------------------------------------------------------------------
// K0: cast fp32 atoms -> bf16 copy (GEMM A-source + gather source, L3-resident)
// ---------------------------------------------------------------------------
__global__ __launch_bounds__(256) void k_cast(const float4* __restrict__ src,
                                              ushort4* __restrict__ dst) {
  size_t i = (size_t)blockIdx.x * 256 + threadIdx.x;   // one float4 -> ushort4
  float4 v = src[i];
  ushort4 o;
  o.x = f2bf(v.x); o.y = f2bf(v.y); o.z = f2bf(v.z); o.w = f2bf(v.w);
  dst[i] = o;
}

// ---------------------------------------------------------------------------
// K1a: build BcatT[d][n][k] (bf16), n,k in [0,256), from fp32 W.
// Virtual B[d][k][n]: k<128 -> neigh (Wrel | 0), k>=128 -> self (Wself | Wg)
// ---------------------------------------------------------------------------
__global__ __launch_bounds__(256) void k_build_b(const float* __restrict__ W,
                                                 unsigned short* __restrict__ BcatT) {
  int idx = blockIdx.x * 256 + threadIdx.x;
  if (idx >= 11 * 256 * 256) return;
  int d = idx >> 16;
  int rem = idx & 65535;
  int n = rem >> 8;
  int k = rem & 255;
  float v = 0.f;
  if (k < 128) {
    if (n < 128 && d >= 1) v = W[(2 * (d - 1)) * 16384 + k * 128 + n];
  } else {
    int ks = k - 128;
    if (n < 128) { int wi = (d >= 1) ? (2 * d - 1) : 20; v = W[wi * 16384 + ks * 128 + n]; }
    else         { int wi = (d >= 1) ? (20 + d)   : 31; v = W[wi * 16384 + ks * 128 + (n - 128)]; }
  }
  BcatT[idx] = f2bf(v);   // idx == d*65536 + n*256 + k
}

// K1b: biascat[d][n] f32: n<128 -> b_rel + b_self (activated), n>=128 -> b_gather
__global__ __launch_bounds__(256) void k_build_bias(const float* __restrict__ b,
                                                    float* __restrict__ biascat) {
  int idx = blockIdx.x * 256 + threadIdx.x;
  if (idx >= 11 * 256) return;
  int d = idx >> 8, n = idx & 255;
  float f;
  if (n < 128) {
    if (d >= 1) f = b[(2 * (d - 1)) * 128 + n] + b[(2 * d - 1) * 128 + n];
    else        f = b[20 * 128 + n];
  } else {
    int j = n - 128;
    f = (d >= 1) ? b[(20 + d) * 128 + j] : b[31 * 128 + j];
  }
  biascat[idx] = f;
}

// ---------------------------------------------------------------------------
// K2: neighbor sums — MLP version (round 6). One wave = 2 consecutive rows.
// ---------------------------------------------------------------------------
template<int D>
__device__ __forceinline__ void nsum_body2(const unsigned* __restrict__ atomsU,
                                           const int* __restrict__ a,   // 2D ints
                                           int lane,
                                           unsigned* __restrict__ out) { // row0 base
  int myIdx = (lane < 2 * D) ? a[lane] : 0;
  unsigned xs[2 * D];
#pragma unroll
  for (int j = 0; j < 2 * D; ++j) {
    int nbr = __shfl(myIdx, j, 64);
    xs[j] = atomsU[(size_t)nbr * 64 + lane];
  }
  float s0a = 0.f, s1a = 0.f, s0b = 0.f, s1b = 0.f;
#pragma unroll
  for (int j = 0; j < D; ++j) {
    s0a += bf2f((unsigned short)(xs[j] & 0xffff));
    s1a += bf2f((unsigned short)(xs[j] >> 16));
  }
#pragma unroll
  for (int j = D; j < 2 * D; ++j) {
    s0b += bf2f((unsigned short)(xs[j] & 0xffff));
    s1b += bf2f((unsigned short)(xs[j] >> 16));
  }
  out[lane]      = (unsigned)f2bf(s0a) | ((unsigned)f2bf(s1a) << 16);
  out[64 + lane] = (unsigned)f2bf(s0b) | ((unsigned)f2bf(s1b) << 16);
}

__global__ __launch_bounds__(256) void k_nsum(const unsigned* __restrict__ atomsU,
                                              AdjPtrs adj,
                                              unsigned* __restrict__ nsumU) {
  int wave = threadIdx.x >> 6;
  int lane = threadIdx.x & 63;
  int row0 = blockIdx.x * 8 + wave * 2;          // 2 rows per wave
  int d = row0 / DEG_COUNT;                       // wave-uniform; both rows same d
  unsigned* out = nsumU + (size_t)row0 * 64;
  if (d == 0) { out[lane] = 0u; out[64 + lane] = 0u; return; }
  int r = row0 - d * DEG_COUNT;
  const int* a = adj.p[d - 1] + (size_t)r * d;   // rows r and r+1: a[0..2d)
  switch (d) {
    case 1:  nsum_body2<1>(atomsU, a, lane, out); break;
    case 2:  nsum_body2<2>(atomsU, a, lane, out); break;
    case 3:  nsum_body2<3>(atomsU, a, lane, out); break;
    case 4:  nsum_body2<4>(atomsU, a, lane, out); break;
    case 5:  nsum_body2<5>(atomsU, a, lane, out); break;
    case 6:  nsum_body2<6>(atomsU, a, lane, out); break;
    case 7:  nsum_body2<7>(atomsU, a, lane, out); break;
    case 8:  nsum_body2<8>(atomsU, a, lane, out); break;
    case 9:  nsum_body2<9>(atomsU, a, lane, out); break;
    default: nsum_body2<10>(atomsU, a, lane, out); break;
  }
}

// ---------------------------------------------------------------------------
// K3: barrier-free streaming MFMA GEMM, bfrag-reuse version.
// Round-6 profile: 2048 ds_read_b128/block (each feeding ONE MFMA) + 1.06e7
// conflict cycles = LDS critical path. Now each bfrag read feeds TWO MFMAs
// (both 16-row sub-chunks), halving LDS reads + conflicts.
// Register budget: acc 128 + af 64 + bf 32 ~= 230 VGPR (cap 256 @ 2 w/SIMD);
// bias/gamma/beta loads moved to the epilogue to free 32 regs through MFMAs.
// Accumulation order per acc unchanged => bit-identical output.
// ---------------------------------------------------------------------------
__global__ __launch_bounds__(512, 2) void k_gemm(
    const unsigned short* __restrict__ atomsBf,
    const unsigned short* __restrict__ nsum,
    const unsigned short* __restrict__ BcatT,    // [11][256][256] n-major
    const float* __restrict__ biascat,           // [11][256]
    const float* __restrict__ gamma,
    const float* __restrict__ beta,
    float* __restrict__ out0,                    // xn FINAL (fp32)
    unsigned short* __restrict__ gath)           // gathered ws (bf16)
{
  const int d = blockIdx.y;
  const int rowTile = blockIdx.x;
  const int tid = threadIdx.x;
  const int lane = tid & 63;
  const int wave = tid >> 6;          // 0..7
  const int m16 = lane & 15;
  const int g = lane >> 4;            // k-group 0..3

  __shared__ unsigned short Bs[256 * 256];   // 128 KiB, swizzled rows of 512B

  const unsigned short* Bd = BcatT + d * 65536;

  // ---- stage B: 512 threads x 16 x 16B = 128KB, swizzled dest ----
#pragma unroll
  for (int it = 0; it < 16; ++it) {
    int flat = it * 512 + tid;        // chunk of 16B; 32 chunks per row
    int row = flat >> 5;
    int c = flat & 31;
    uint4 v = *(const uint4*)(Bd + row * 256 + c * 8);
    int kb = (c * 16) ^ ((row & 7) << 4);
    *(uint4*)((char*)Bs + row * 512 + kb) = v;
  }

  // ---- hoist A-frag loads for both 16-row chunks (hide under barrier) ----
  const int rowBase0 = rowTile * 256 + wave * 32;
  bf16x8 af0[8], af1[8];
  {
    int rbL = rowBase0 + m16; if (rbL > DEG_COUNT - 1) rbL = DEG_COUNT - 1;
    size_t gr = (size_t)d * DEG_COUNT + rbL;
#pragma unroll
    for (int ks = 0; ks < 4; ++ks)
      af0[ks] = *(const bf16x8*)(nsum + gr * 128 + ks * 32 + g * 8);
#pragma unroll
    for (int ks = 4; ks < 8; ++ks)
      af0[ks] = *(const bf16x8*)(atomsBf + gr * 128 + (ks - 4) * 32 + g * 8);
  }
  {
    int rbL = rowBase0 + 16 + m16; if (rbL > DEG_COUNT - 1) rbL = DEG_COUNT - 1;
    size_t gr = (size_t)d * DEG_COUNT + rbL;
#pragma unroll
    for (int ks = 0; ks < 4; ++ks)
      af1[ks] = *(const bf16x8*)(nsum + gr * 128 + ks * 32 + g * 8);
#pragma unroll
    for (int ks = 4; ks < 8; ++ks)
      af1[ks] = *(const bf16x8*)(atomsBf + gr * 128 + (ks - 4) * 32 + g * 8);
  }

  __syncthreads();   // the only block-wide barrier

  const int ldsMask = (m16 & 7) << 4;

  f32x4 acc0[16], acc1[16];
#pragma unroll
  for (int ct = 0; ct < 16; ++ct) {
    acc0[ct] = (f32x4){0.f, 0.f, 0.f, 0.f};
    acc1[ct] = (f32x4){0.f, 0.f, 0.f, 0.f};
  }

#pragma unroll
  for (int ct = 0; ct < 16; ++ct) {
    const char* bbase = (const char*)Bs + (ct * 16 + m16) * 512;
    bf16x8 bf[8];
#pragma unroll
    for (int ks = 0; ks < 8; ++ks)
      bf[ks] = *(const bf16x8*)(bbase + ((ks * 64 + g * 16) ^ ldsMask));
#pragma unroll
    for (int ks = 0; ks < 8; ++ks) {
      acc0[ct] = __builtin_amdgcn_mfma_f32_16x16x32_bf16(af0[ks], bf[ks], acc0[ct], 0, 0, 0);
      acc1[ct] = __builtin_amdgcn_mfma_f32_16x16x32_bf16(af1[ks], bf[ks], acc1[ct], 0, 0, 0);
    }
  }

  // ---- epilogue (per sub): bias, LN over cols 0..127, stores ----
  float bias_[16], gam[8], bet[8];
#pragma unroll
  for (int ct = 0; ct < 16; ++ct) bias_[ct] = biascat[d * 256 + ct * 16 + m16];
#pragma unroll
  for (int ct = 0; ct < 8; ++ct) {
    gam[ct] = gamma[ct * 16 + m16];
    bet[ct] = beta[ct * 16 + m16];
  }

#pragma unroll
  for (int sub = 0; sub < 2; ++sub) {
    const int rowBase = rowBase0 + sub * 16;
    f32x4* acc = (sub == 0) ? acc0 : acc1;

#pragma unroll
    for (int ct = 0; ct < 16; ++ct)
#pragma unroll
      for (int r = 0; r < 4; ++r) acc[ct][r] += bias_[ct];

    float s[4], qq[4];
#pragma unroll
    for (int r = 0; r < 4; ++r) {
      s[r] = 0.f; qq[r] = 0.f;
#pragma unroll
      for (int ct = 0; ct < 8; ++ct) {
        float v = acc[ct][r];
        s[r] += v; qq[r] += v * v;
      }
    }
#pragma unroll
    for (int off = 8; off >= 1; off >>= 1) {
#pragma unroll
      for (int r = 0; r < 4; ++r) {
        s[r]  += __shfl_xor(s[r],  off, 64);
        qq[r] += __shfl_xor(qq[r], off, 64);
      }
    }

#pragma unroll
    for (int r = 0; r < 4; ++r) {
      int rb = rowBase + g * 4 + r;
      float mean = s[r] * (1.0f / 128.0f);
      float var  = qq[r] * (1.0f / 128.0f) - mean * mean;
      float inv  = 1.0f / (sqrtf(var + 1e-5f) + 1e-5f);   // ref: sqrt(var+eps)+eps
      if (rb < DEG_COUNT) {
        size_t grow = (size_t)d * DEG_COUNT + rb;
#pragma unroll
        for (int ct = 0; ct < 8; ++ct)
          out0[grow * 128 + ct * 16 + m16] = gam[ct] * ((acc[ct][r] - mean) * inv) + bet[ct];
#pragma unroll
        for (int ct = 8; ct < 16; ++ct)
          gath[grow * 128 + (ct - 8) * 16 + m16] = f2bf(acc[ct][r]);
      }
    }
  }
}

// ---------------------------------------------------------------------------
// Counting sort by membership — atomic-contention-free 3-phase version.
// ---------------------------------------------------------------------------
__global__ __launch_bounds__(256) void k_hist2(const int* __restrict__ membership,
                                               int* __restrict__ blockHist) {
  __shared__ int bins[BATCH];
  int tid = threadIdx.x;
  if (tid < BATCH) bins[tid] = 0;
  __syncthreads();
  const int chunk = (N_ATOMS + SORT_BLOCKS - 1) / SORT_BLOCKS;
  int lo = blockIdx.x * chunk, hi = min(lo + chunk, N_ATOMS);
  for (int i = lo + tid; i < hi; i += 256)
    atomicAdd(&bins[membership[i]], 1);
  __syncthreads();
  if (tid < BATCH) blockHist[blockIdx.x * BATCH + tid] = bins[tid];
}

// 1 block, 128 threads: thread m = bin m. Column-sum, exclusive bin scan,
// then per-block running offsets off[b][m].
__global__ __launch_bounds__(128) void k_scan2(const int* __restrict__ blockHist,
                                               int* __restrict__ off,     // [SORT_BLOCKS][128]
                                               int* __restrict__ base,
                                               int* __restrict__ hist) {
  int m = threadIdx.x;
  int tot = 0;
  for (int b = 0; b < SORT_BLOCKS; ++b) tot += blockHist[b * BATCH + m];
  hist[m] = tot;
  __shared__ int t[BATCH];
  t[m] = tot;
  __syncthreads();
  int acc = 0;
  for (int i = 0; i < m; ++i) acc += t[i];   // 128 LDS reads max — trivial
  base[m] = acc;
  int run = acc;
  for (int b = 0; b < SORT_BLOCKS; ++b) {
    off[b * BATCH + m] = run;
    run += blockHist[b * BATCH + m];
  }
}

// Per-block scatter: seed LDS bins with this block's global offsets, then
// block-local LDS int atomics (<=1.3K/block) + plain 4B global writes.
__global__ __launch_bounds__(256) void k_scatter2(const int* __restrict__ membership,
                                                  const int* __restrict__ off,
                                                  int* __restrict__ perm) {
  __shared__ int bins[BATCH];
  int tid = threadIdx.x;
  if (tid < BATCH) bins[tid] = off[blockIdx.x * BATCH + tid];
  __syncthreads();
  const int chunk = (N_ATOMS + SORT_BLOCKS - 1) / SORT_BLOCKS;
  int lo = blockIdx.x * chunk, hi = min(lo + chunk, N_ATOMS);
  for (int i = lo + tid; i < hi; i += 256) {
    int m = membership[i];
    int pos = atomicAdd(&bins[m], 1);
    perm[pos] = i;
  }
}

// ---------------------------------------------------------------------------
// K_reduce: fused segment-max(xn) + segment-sum(gath), atomic-free.
// ---------------------------------------------------------------------------
__global__ __launch_bounds__(512) void k_reduce(
    const float2* __restrict__ xnV,         // out0 as float2
    const unsigned* __restrict__ gathU,
    const int* __restrict__ perm,
    const int* __restrict__ base,
    const int* __restrict__ hist,
    float2* __restrict__ psum4,             // [4][128][64] float2
    float2* __restrict__ pmax4)             // [4][128][64] float2
{
  const int m = blockIdx.x >> 2;
  const int s = blockIdx.x & 3;
  const int b0 = base[m], cnt = hist[m];
  const int lo = b0 + (cnt * s) / 4;
  const int hi = b0 + (cnt * (s + 1)) / 4;
  const int wave = threadIdx.x >> 6, lane = threadIdx.x & 63;

  const float NEG_INF = __int_as_float((int)NEG_INF_BITS);
  float mx0 = NEG_INF, mx1 = NEG_INF, s0 = 0.f, s1 = 0.f;

#pragma unroll 4
  for (int i = lo + wave; i < hi; i += 8) {
    int r = perm[i];
    float2 x = xnV[(size_t)r * 64 + lane];
    unsigned gg = gathU[(size_t)r * 64 + lane];
    mx0 = fmaxf(mx0, x.x);
    mx1 = fmaxf(mx1, x.y);
    s0 += bf2f((unsigned short)(gg & 0xffff));
    s1 += bf2f((unsigned short)(gg >> 16));
  }

  __shared__ float2 sumT[8][64];
  __shared__ float2 maxT[8][64];
  sumT[wave][lane] = make_float2(s0, s1);
  maxT[wave][lane] = make_float2(mx0, mx1);
  __syncthreads();

  if (threadIdx.x < 64) {
    int l = threadIdx.x;
    float2 ss = sumT[0][l];
    float2 mm = maxT[0][l];
#pragma unroll
    for (int w = 1; w < 8; ++w) {
      float2 a = sumT[w][l]; ss.x += a.x; ss.y += a.y;
      float2 b = maxT[w][l]; mm.x = fmaxf(mm.x, b.x); mm.y = fmaxf(mm.y, b.y);
    }
    psum4[(s * 128 + m) * 64 + l] = ss;
    pmax4[(s * 128 + m) * 64 + l] = mm;
  }
}

// K6: merge 4 slices; norm sum -> yn (out1); max -> g (out2). fp32.
__global__ __launch_bounds__(128) void k_final(
    const float* __restrict__ psum4,        // [4][128][128]
    const float* __restrict__ pmax4,
    const float* __restrict__ gamma,
    const float* __restrict__ beta,
    float* __restrict__ out1,
    float* __restrict__ out2)
{
  int m = blockIdx.x;
  int j = threadIdx.x;
  float s = 0.f, g = __int_as_float((int)NEG_INF_BITS);
#pragma unroll
  for (int sl = 0; sl < 4; ++sl) {
    s += psum4[(sl * 128 + m) * 128 + j];
    g = fmaxf(g, pmax4[(sl * 128 + m) * 128 + j]);
  }
  out2[m * 128 + j] = g;

  float ws_ = s, wq = s * s;
#pragma unroll
  for (int off = 32; off >= 1; off >>= 1) {
    ws_ += __shfl_xor(ws_, off, 64);
    wq  += __shfl_xor(wq, off, 64);
  }
  __shared__ float red[4];
  int wave = j >> 6, lane = j & 63;
  if (lane == 0) { red[wave * 2] = ws_; red[wave * 2 + 1] = wq; }
  __syncthreads();
  float S = red[0] + red[2], Q = red[1] + red[3];
  float mean = S * (1.f / 128.f);
  float var = Q * (1.f / 128.f) - mean * mean;
  float inv = 1.f / (sqrtf(var + 1e-5f) + 1e-5f);
  float yn = gamma[j] * ((s - mean) * inv) + beta[j];
  out1[m * 128 + j] = yn;
}

// ---------------------------------------------------------------------------
extern "C" void kernel_launch(void* const* d_in, const int* in_sizes, int n_in,
                              void* d_out, int out_size, void* d_ws, size_t ws_size,
                              hipStream_t stream) {
  const float* atoms = (const float*)d_in[0];
  // d_in[1] = deg_slice (unused; buckets are static)
  const int* membership = (const int*)d_in[2];
  AdjPtrs adj;
  for (int i = 0; i < 10; ++i) adj.p[i] = (const int*)d_in[3 + i];
  const float* W     = (const float*)d_in[13];
  const float* b     = (const float*)d_in[14];
  const float* gamma = (const float*)d_in[15];
  const float* beta  = (const float*)d_in[16];

  char* ws = (char*)d_ws;
  size_t off = 0;
  unsigned short* atomsBf = (unsigned short*)(ws + off); off += (size_t)N_ATOMS * 128 * 2;
  unsigned short* nsum    = (unsigned short*)(ws + off); off += (size_t)N_ATOMS * 128 * 2;
  unsigned short* gath    = (unsigned short*)(ws + off); off += (size_t)N_ATOMS * 128 * 2;
  unsigned short* BcatT   = (unsigned short*)(ws + off); off += (size_t)11 * 256 * 256 * 2;
  float* biascat          = (float*)(ws + off);          off += (size_t)11 * 256 * 4;

  // Sort + reduction scratch reuses atomsBf's space (dead after k_gemm):
  char* scr = (char*)atomsBf;
  int* perm      = (int*)(scr);                          // 1.32 MB
  int* hist      = (int*)(scr + 2 * 1024 * 1024);        // 512 B
  int* base_     = (int*)(scr + 2 * 1024 * 1024 + 1024);
  int* blockHist = (int*)(scr + 2 * 1024 * 1024 + 4096); // 128 KB
  int* offTab    = (int*)(scr + 2 * 1024 * 1024 + 4096 + SORT_BLOCKS * BATCH * 4); // 128 KB
  float* psum4   = (float*)(scr + 3 * 1024 * 1024);      // 256 KB
  float* pmax4   = (float*)(scr + 3 * 1024 * 1024 + 256 * 1024);

  float* out0 = (float*)d_out;
  float* out1 = out0 + (size_t)N_ATOMS * 128;
  float* out2 = out1 + 16384;

  hipLaunchKernelGGL(k_cast, dim3(N_ATOMS * 128 / 4 / 256), dim3(256), 0, stream,
                     (const float4*)atoms, (ushort4*)atomsBf);
  hipLaunchKernelGGL(k_build_b, dim3((11 * 256 * 256 + 255) / 256), dim3(256), 0, stream, W, BcatT);
  hipLaunchKernelGGL(k_build_bias, dim3((11 * 256 + 255) / 256), dim3(256), 0, stream, b, biascat);
  hipLaunchKernelGGL(k_nsum, dim3(N_ATOMS / 8), dim3(256), 0, stream,
                     (const unsigned*)atomsBf, adj, (unsigned*)nsum);
  hipLaunchKernelGGL(k_gemm, dim3(118, 11), dim3(512), 0, stream,
                     atomsBf, nsum, BcatT, biascat, gamma, beta, out0, gath);
  // counting sort (scratch overlays dead atomsBf; zero global atomics)
  hipLaunchKernelGGL(k_hist2, dim3(SORT_BLOCKS), dim3(256), 0, stream, membership, blockHist);
  hipLaunchKernelGGL(k_scan2, dim3(1), dim3(128), 0, stream, blockHist, offTab, base_, hist);
  hipLaunchKernelGGL(k_scatter2, dim3(SORT_BLOCKS), dim3(256), 0, stream, membership, offTab, perm);
  // fused atomic-free segment max + sum
  hipLaunchKernelGGL(k_reduce, dim3(512), dim3(512), 0, stream,
                     (const float2*)out0, (const unsigned*)gath, perm, base_, hist,
                     (float2*)psum4, (float2*)pmax4);
  hipLaunchKernelGGL(k_final, dim3(128), dim3(128), 0, stream,
                     psum4, pmax4, gamma, beta, out1, out2);
}

// Round 8
// 554.175 us; speedup vs baseline: 1.6562x; 1.0127x over previous
//
#include <hip/hip_runtime.h>
#include <stdint.h>

#define MAX_DEG   10
#define DEG_COUNT 30000
#define N_ATOMS   330000      // 11 * 30000
#define NF        128
#define BATCH     128
#define SORT_BLOCKS 256

typedef __attribute__((ext_vector_type(8))) short bf16x8;   // 8 bf16 (4 VGPRs)
typedef __attribute__((ext_vector_type(4))) float f32x4;

__device__ __forceinline__ float bf2f(unsigned short h) {
  union { unsigned u; float f; } v; v.u = ((unsigned)h) << 16; return v.f;
}
__device__ __forceinline__ unsigned short f2bf(float f) {
  union { float f; unsigned u; } v; v.f = f;
  unsigned u = v.u;
  unsigned r = (u + 0x7fffu + ((u >> 16) & 1u)) >> 16;   // RNE
  return (unsigned short)r;
}

struct AdjPtrs { const int* p[10]; };

#define NEG_INF_BITS 0xFF800000

// ---------------------------------------------------------------------------
// K0: cast fp32 atoms -> bf16 copy (GEMM A-source + gather source, L3-resident)
// ---------------------------------------------------------------------------
__global__ __launch_bounds__(256) void k_cast(const float4* __restrict__ src,
                                              ushort4* __restrict__ dst) {
  size_t i = (size_t)blockIdx.x * 256 + threadIdx.x;   // one float4 -> ushort4
  float4 v = src[i];
  ushort4 o;
  o.x = f2bf(v.x); o.y = f2bf(v.y); o.z = f2bf(v.z); o.w = f2bf(v.w);
  dst[i] = o;
}

// ---------------------------------------------------------------------------
// K1a: build BcatT[d][n][k] (bf16), n,k in [0,256), from fp32 W.
// Virtual B[d][k][n]: k<128 -> neigh (Wrel | 0), k>=128 -> self (Wself | Wg)
// ---------------------------------------------------------------------------
__global__ __launch_bounds__(256) void k_build_b(const float* __restrict__ W,
                                                 unsigned short* __restrict__ BcatT) {
  int idx = blockIdx.x * 256 + threadIdx.x;
  if (idx >= 11 * 256 * 256) return;
  int d = idx >> 16;
  int rem = idx & 65535;
  int n = rem >> 8;
  int k = rem & 255;
  float v = 0.f;
  if (k < 128) {
    if (n < 128 && d >= 1) v = W[(2 * (d - 1)) * 16384 + k * 128 + n];
  } else {
    int ks = k - 128;
    if (n < 128) { int wi = (d >= 1) ? (2 * d - 1) : 20; v = W[wi * 16384 + ks * 128 + n]; }
    else         { int wi = (d >= 1) ? (20 + d)   : 31; v = W[wi * 16384 + ks * 128 + (n - 128)]; }
  }
  BcatT[idx] = f2bf(v);   // idx == d*65536 + n*256 + k
}

// K1b: biascat[d][n] f32: n<128 -> b_rel + b_self (activated), n>=128 -> b_gather
__global__ __launch_bounds__(256) void k_build_bias(const float* __restrict__ b,
                                                    float* __restrict__ biascat) {
  int idx = blockIdx.x * 256 + threadIdx.x;
  if (idx >= 11 * 256) return;
  int d = idx >> 8, n = idx & 255;
  float f;
  if (n < 128) {
    if (d >= 1) f = b[(2 * (d - 1)) * 128 + n] + b[(2 * d - 1) * 128 + n];
    else        f = b[20 * 128 + n];
  } else {
    int j = n - 128;
    f = (d >= 1) ? b[(20 + d) * 128 + j] : b[31 * 128 + j];
  }
  biascat[idx] = f;
}

// ---------------------------------------------------------------------------
// Phase-0 helper (fused former k_nsum): one wave computes 32 nsum rows of its
// block into LDS, 2 rows/iter (wave-coalesced gathers, 2D loads in flight).
// fp32 accumulate j-ascending + f2bf => bit-identical to the old k_nsum.
// LDS rows XOR-swizzled (word ^= (row&7)<<2) so af reads are conflict-free.
// ---------------------------------------------------------------------------
template<int D>
__device__ __forceinline__ void nsum_phase0(const unsigned* __restrict__ atomsU,
                                            const int* __restrict__ abase,
                                            unsigned* __restrict__ NS,
                                            int rowTile, int wave, int lane) {
  for (int it = 0; it < 16; ++it) {
    int iloc = wave * 32 + it * 2;
    int r0 = rowTile * 256 + iloc;
    int sw0 = lane ^ ((iloc & 7) << 2);
    int sw1 = lane ^ (((iloc + 1) & 7) << 2);
    if (r0 < DEG_COUNT - 1) {                    // normal pair (r0, r0+1)
      const int* a = abase + (size_t)r0 * D;
      int myIdx = (lane < 2 * D) ? a[lane] : 0;
      unsigned xs[2 * D];
#pragma unroll
      for (int j = 0; j < 2 * D; ++j) {
        int nbr = __shfl(myIdx, j, 64);
        xs[j] = atomsU[(size_t)nbr * 64 + lane];
      }
      float s0a = 0.f, s1a = 0.f, s0b = 0.f, s1b = 0.f;
#pragma unroll
      for (int j = 0; j < D; ++j) {
        s0a += bf2f((unsigned short)(xs[j] & 0xffff));
        s1a += bf2f((unsigned short)(xs[j] >> 16));
      }
#pragma unroll
      for (int j = D; j < 2 * D; ++j) {
        s0b += bf2f((unsigned short)(xs[j] & 0xffff));
        s1b += bf2f((unsigned short)(xs[j] >> 16));
      }
      NS[(size_t)iloc * 64 + sw0]       = (unsigned)f2bf(s0a) | ((unsigned)f2bf(s1a) << 16);
      NS[(size_t)(iloc + 1) * 64 + sw1] = (unsigned)f2bf(s0b) | ((unsigned)f2bf(s1b) << 16);
    } else {                                     // tail: both rows clamp to 29999
      const int* a = abase + (size_t)(DEG_COUNT - 1) * D;
      int myIdx = (lane < D) ? a[lane] : 0;
      unsigned xs[D];
#pragma unroll
      for (int j = 0; j < D; ++j) {
        int nbr = __shfl(myIdx, j, 64);
        xs[j] = atomsU[(size_t)nbr * 64 + lane];
      }
      float s0 = 0.f, s1 = 0.f;
#pragma unroll
      for (int j = 0; j < D; ++j) {
        s0 += bf2f((unsigned short)(xs[j] & 0xffff));
        s1 += bf2f((unsigned short)(xs[j] >> 16));
      }
      unsigned p = (unsigned)f2bf(s0) | ((unsigned)f2bf(s1) << 16);
      NS[(size_t)iloc * 64 + sw0] = p;
      NS[(size_t)(iloc + 1) * 64 + sw1] = p;
    }
  }
}

// ---------------------------------------------------------------------------
// K3: fused nsum + barrier-free streaming MFMA GEMM.
// Phase 0: block's 256 nsum rows -> LDS (swizzled), af ks0-3 read from LDS.
// Then LDS reused for the 128KB B panel; MFMA + LN epilogue as round 7.
// Removes the k_nsum kernel + its 82MB write + 84.5MB re-read.
// ---------------------------------------------------------------------------
__global__ __launch_bounds__(512, 2) void k_gemm(
    const unsigned short* __restrict__ atomsBf,
    AdjPtrs adj,
    const unsigned short* __restrict__ BcatT,    // [11][256][256] n-major
    const float* __restrict__ biascat,           // [11][256]
    const float* __restrict__ gamma,
    const float* __restrict__ beta,
    float* __restrict__ out0,                    // xn FINAL (fp32)
    unsigned short* __restrict__ gath)           // gathered ws (bf16)
{
  const int d = blockIdx.y;
  const int rowTile = blockIdx.x;
  const int tid = threadIdx.x;
  const int lane = tid & 63;
  const int wave = tid >> 6;          // 0..7
  const int m16 = lane & 15;
  const int g = lane >> 4;            // k-group 0..3

  __shared__ unsigned short Bs[256 * 256];   // 128 KiB; phase0 uses first 64KB
  unsigned* NS = (unsigned*)Bs;              // [256 rows][64 words], swizzled

  const unsigned short* Bd = BcatT + d * 65536;
  const unsigned* atomsU = (const unsigned*)atomsBf;

  // ---- self A-frags (ks 4-7) from global first (overlap with phase 0) ----
  const int rowBase0 = rowTile * 256 + wave * 32;
  bf16x8 af0[8], af1[8];
  {
    int rbL = rowBase0 + m16; if (rbL > DEG_COUNT - 1) rbL = DEG_COUNT - 1;
    size_t gr = (size_t)d * DEG_COUNT + rbL;
#pragma unroll
    for (int ks = 4; ks < 8; ++ks)
      af0[ks] = *(const bf16x8*)(atomsBf + gr * 128 + (ks - 4) * 32 + g * 8);
  }
  {
    int rbL = rowBase0 + 16 + m16; if (rbL > DEG_COUNT - 1) rbL = DEG_COUNT - 1;
    size_t gr = (size_t)d * DEG_COUNT + rbL;
#pragma unroll
    for (int ks = 4; ks < 8; ++ks)
      af1[ks] = *(const bf16x8*)(atomsBf + gr * 128 + (ks - 4) * 32 + g * 8);
  }

  // ---- phase 0: fused nsum into LDS; af ks0-3 from LDS ----
  if (d > 0) {
    const int* abase = adj.p[d - 1];
    switch (d) {
      case 1:  nsum_phase0<1>(atomsU, abase, NS, rowTile, wave, lane); break;
      case 2:  nsum_phase0<2>(atomsU, abase, NS, rowTile, wave, lane); break;
      case 3:  nsum_phase0<3>(atomsU, abase, NS, rowTile, wave, lane); break;
      case 4:  nsum_phase0<4>(atomsU, abase, NS, rowTile, wave, lane); break;
      case 5:  nsum_phase0<5>(atomsU, abase, NS, rowTile, wave, lane); break;
      case 6:  nsum_phase0<6>(atomsU, abase, NS, rowTile, wave, lane); break;
      case 7:  nsum_phase0<7>(atomsU, abase, NS, rowTile, wave, lane); break;
      case 8:  nsum_phase0<8>(atomsU, abase, NS, rowTile, wave, lane); break;
      case 9:  nsum_phase0<9>(atomsU, abase, NS, rowTile, wave, lane); break;
      default: nsum_phase0<10>(atomsU, abase, NS, rowTile, wave, lane); break;
    }
    __syncthreads();
    const char* nsb = (const char*)NS;
    const int rowb0 = (wave * 32 + m16) * 256;        // byte base, row m16
    const int rowb1 = (wave * 32 + 16 + m16) * 256;   // byte base, row m16+16
    const int sw = (m16 & 7) << 4;
#pragma unroll
    for (int ks = 0; ks < 4; ++ks) {
      af0[ks] = *(const bf16x8*)(nsb + ((rowb0 + ks * 64 + g * 16) ^ sw));
      af1[ks] = *(const bf16x8*)(nsb + ((rowb1 + ks * 64 + g * 16) ^ sw));
    }
    __syncthreads();   // protect NS before B-panel overwrite
  } else {
    bf16x8 z = {0, 0, 0, 0, 0, 0, 0, 0};
#pragma unroll
    for (int ks = 0; ks < 4; ++ks) { af0[ks] = z; af1[ks] = z; }
  }

  // ---- stage B: 512 threads x 16 x 16B = 128KB, swizzled dest ----
#pragma unroll
  for (int it = 0; it < 16; ++it) {
    int flat = it * 512 + tid;        // chunk of 16B; 32 chunks per row
    int row = flat >> 5;
    int c = flat & 31;
    uint4 v = *(const uint4*)(Bd + row * 256 + c * 8);
    int kb = (c * 16) ^ ((row & 7) << 4);
    *(uint4*)((char*)Bs + row * 512 + kb) = v;
  }

  __syncthreads();

  const int ldsMask = (m16 & 7) << 4;

  f32x4 acc0[16], acc1[16];
#pragma unroll
  for (int ct = 0; ct < 16; ++ct) {
    acc0[ct] = (f32x4){0.f, 0.f, 0.f, 0.f};
    acc1[ct] = (f32x4){0.f, 0.f, 0.f, 0.f};
  }

#pragma unroll
  for (int ct = 0; ct < 16; ++ct) {
    const char* bbase = (const char*)Bs + (ct * 16 + m16) * 512;
    bf16x8 bf[8];
#pragma unroll
    for (int ks = 0; ks < 8; ++ks)
      bf[ks] = *(const bf16x8*)(bbase + ((ks * 64 + g * 16) ^ ldsMask));
#pragma unroll
    for (int ks = 0; ks < 8; ++ks) {
      acc0[ct] = __builtin_amdgcn_mfma_f32_16x16x32_bf16(af0[ks], bf[ks], acc0[ct], 0, 0, 0);
      acc1[ct] = __builtin_amdgcn_mfma_f32_16x16x32_bf16(af1[ks], bf[ks], acc1[ct], 0, 0, 0);
    }
  }

  // ---- epilogue (per sub): bias, LN over cols 0..127, stores ----
  float bias_[16], gam[8], bet[8];
#pragma unroll
  for (int ct = 0; ct < 16; ++ct) bias_[ct] = biascat[d * 256 + ct * 16 + m16];
#pragma unroll
  for (int ct = 0; ct < 8; ++ct) {
    gam[ct] = gamma[ct * 16 + m16];
    bet[ct] = beta[ct * 16 + m16];
  }

#pragma unroll
  for (int sub = 0; sub < 2; ++sub) {
    const int rowBase = rowBase0 + sub * 16;
    f32x4* acc = (sub == 0) ? acc0 : acc1;

#pragma unroll
    for (int ct = 0; ct < 16; ++ct)
#pragma unroll
      for (int r = 0; r < 4; ++r) acc[ct][r] += bias_[ct];

    float s[4], qq[4];
#pragma unroll
    for (int r = 0; r < 4; ++r) {
      s[r] = 0.f; qq[r] = 0.f;
#pragma unroll
      for (int ct = 0; ct < 8; ++ct) {
        float v = acc[ct][r];
        s[r] += v; qq[r] += v * v;
      }
    }
#pragma unroll
    for (int off = 8; off >= 1; off >>= 1) {
#pragma unroll
      for (int r = 0; r < 4; ++r) {
        s[r]  += __shfl_xor(s[r],  off, 64);
        qq[r] += __shfl_xor(qq[r], off, 64);
      }
    }

#pragma unroll
    for (int r = 0; r < 4; ++r) {
      int rb = rowBase + g * 4 + r;
      float mean = s[r] * (1.0f / 128.0f);
      float var  = qq[r] * (1.0f / 128.0f) - mean * mean;
      float inv  = 1.0f / (sqrtf(var + 1e-5f) + 1e-5f);   // ref: sqrt(var+eps)+eps
      if (rb < DEG_COUNT) {
        size_t grow = (size_t)d * DEG_COUNT + rb;
#pragma unroll
        for (int ct = 0; ct < 8; ++ct)
          out0[grow * 128 + ct * 16 + m16] = gam[ct] * ((acc[ct][r] - mean) * inv) + bet[ct];
#pragma unroll
        for (int ct = 8; ct < 16; ++ct)
          gath[grow * 128 + (ct - 8) * 16 + m16] = f2bf(acc[ct][r]);
      }
    }
  }
}

// ---------------------------------------------------------------------------
// Counting sort by membership — atomic-contention-free 3-phase version.
// ---------------------------------------------------------------------------
__global__ __launch_bounds__(256) void k_hist2(const int* __restrict__ membership,
                                               int* __restrict__ blockHist) {
  __shared__ int bins[BATCH];
  int tid = threadIdx.x;
  if (tid < BATCH) bins[tid] = 0;
  __syncthreads();
  const int chunk = (N_ATOMS + SORT_BLOCKS - 1) / SORT_BLOCKS;
  int lo = blockIdx.x * chunk, hi = min(lo + chunk, N_ATOMS);
  for (int i = lo + tid; i < hi; i += 256)
    atomicAdd(&bins[membership[i]], 1);
  __syncthreads();
  if (tid < BATCH) blockHist[blockIdx.x * BATCH + tid] = bins[tid];
}

// 1 block, 128 threads: thread m = bin m. Column-sum, exclusive bin scan,
// then per-block running offsets off[b][m].
__global__ __launch_bounds__(128) void k_scan2(const int* __restrict__ blockHist,
                                               int* __restrict__ off,     // [SORT_BLOCKS][128]
                                               int* __restrict__ base,
                                               int* __restrict__ hist) {
  int m = threadIdx.x;
  int tot = 0;
  for (int b = 0; b < SORT_BLOCKS; ++b) tot += blockHist[b * BATCH + m];
  hist[m] = tot;
  __shared__ int t[BATCH];
  t[m] = tot;
  __syncthreads();
  int acc = 0;
  for (int i = 0; i < m; ++i) acc += t[i];   // 128 LDS reads max — trivial
  base[m] = acc;
  int run = acc;
  for (int b = 0; b < SORT_BLOCKS; ++b) {
    off[b * BATCH + m] = run;
    run += blockHist[b * BATCH + m];
  }
}

// Per-block scatter: seed LDS bins with this block's global offsets, then
// block-local LDS int atomics (<=1.3K/block) + plain 4B global writes.
__global__ __launch_bounds__(256) void k_scatter2(const int* __restrict__ membership,
                                                  const int* __restrict__ off,
                                                  int* __restrict__ perm) {
  __shared__ int bins[BATCH];
  int tid = threadIdx.x;
  if (tid < BATCH) bins[tid] = off[blockIdx.x * BATCH + tid];
  __syncthreads();
  const int chunk = (N_ATOMS + SORT_BLOCKS - 1) / SORT_BLOCKS;
  int lo = blockIdx.x * chunk, hi = min(lo + chunk, N_ATOMS);
  for (int i = lo + tid; i < hi; i += 256) {
    int m = membership[i];
    int pos = atomicAdd(&bins[m], 1);
    perm[pos] = i;
  }
}

// ---------------------------------------------------------------------------
// K_reduce: fused segment-max(xn) + segment-sum(gath), atomic-free.
// ---------------------------------------------------------------------------
__global__ __launch_bounds__(512) void k_reduce(
    const float2* __restrict__ xnV,         // out0 as float2
    const unsigned* __restrict__ gathU,
    const int* __restrict__ perm,
    const int* __restrict__ base,
    const int* __restrict__ hist,
    float2* __restrict__ psum4,             // [4][128][64] float2
    float2* __restrict__ pmax4)             // [4][128][64] float2
{
  const int m = blockIdx.x >> 2;
  const int s = blockIdx.x & 3;
  const int b0 = base[m], cnt = hist[m];
  const int lo = b0 + (cnt * s) / 4;
  const int hi = b0 + (cnt * (s + 1)) / 4;
  const int wave = threadIdx.x >> 6, lane = threadIdx.x & 63;

  const float NEG_INF = __int_as_float((int)NEG_INF_BITS);
  float mx0 = NEG_INF, mx1 = NEG_INF, s0 = 0.f, s1 = 0.f;

#pragma unroll 4
  for (int i = lo + wave; i < hi; i += 8) {
    int r = perm[i];
    float2 x = xnV[(size_t)r * 64 + lane];
    unsigned gg = gathU[(size_t)r * 64 + lane];
    mx0 = fmaxf(mx0, x.x);
    mx1 = fmaxf(mx1, x.y);
    s0 += bf2f((unsigned short)(gg & 0xffff));
    s1 += bf2f((unsigned short)(gg >> 16));
  }

  __shared__ float2 sumT[8][64];
  __shared__ float2 maxT[8][64];
  sumT[wave][lane] = make_float2(s0, s1);
  maxT[wave][lane] = make_float2(mx0, mx1);
  __syncthreads();

  if (threadIdx.x < 64) {
    int l = threadIdx.x;
    float2 ss = sumT[0][l];
    float2 mm = maxT[0][l];
#pragma unroll
    for (int w = 1; w < 8; ++w) {
      float2 a = sumT[w][l]; ss.x += a.x; ss.y += a.y;
      float2 b = maxT[w][l]; mm.x = fmaxf(mm.x, b.x); mm.y = fmaxf(mm.y, b.y);
    }
    psum4[(s * 128 + m) * 64 + l] = ss;
    pmax4[(s * 128 + m) * 64 + l] = mm;
  }
}

// K6: merge 4 slices; norm sum -> yn (out1); max -> g (out2). fp32.
__global__ __launch_bounds__(128) void k_final(
    const float* __restrict__ psum4,        // [4][128][128]
    const float* __restrict__ pmax4,
    const float* __restrict__ gamma,
    const float* __restrict__ beta,
    float* __restrict__ out1,
    float* __restrict__ out2)
{
  int m = blockIdx.x;
  int j = threadIdx.x;
  float s = 0.f, g = __int_as_float((int)NEG_INF_BITS);
#pragma unroll
  for (int sl = 0; sl < 4; ++sl) {
    s += psum4[(sl * 128 + m) * 128 + j];
    g = fmaxf(g, pmax4[(sl * 128 + m) * 128 + j]);
  }
  out2[m * 128 + j] = g;

  float ws_ = s, wq = s * s;
#pragma unroll
  for (int off = 32; off >= 1; off >>= 1) {
    ws_ += __shfl_xor(ws_, off, 64);
    wq  += __shfl_xor(wq, off, 64);
  }
  __shared__ float red[4];
  int wave = j >> 6, lane = j & 63;
  if (lane == 0) { red[wave * 2] = ws_; red[wave * 2 + 1] = wq; }
  __syncthreads();
  float S = red[0] + red[2], Q = red[1] + red[3];
  float mean = S * (1.f / 128.f);
  float var = Q * (1.f / 128.f) - mean * mean;
  float inv = 1.f / (sqrtf(var + 1e-5f) + 1e-5f);
  float yn = gamma[j] * ((s - mean) * inv) + beta[j];
  out1[m * 128 + j] = yn;
}

// ---------------------------------------------------------------------------
extern "C" void kernel_launch(void* const* d_in, const int* in_sizes, int n_in,
                              void* d_out, int out_size, void* d_ws, size_t ws_size,
                              hipStream_t stream) {
  const float* atoms = (const float*)d_in[0];
  // d_in[1] = deg_slice (unused; buckets are static)
  const int* membership = (const int*)d_in[2];
  AdjPtrs adj;
  for (int i = 0; i < 10; ++i) adj.p[i] = (const int*)d_in[3 + i];
  const float* W     = (const float*)d_in[13];
  const float* b     = (const float*)d_in[14];
  const float* gamma = (const float*)d_in[15];
  const float* beta  = (const float*)d_in[16];

  char* ws = (char*)d_ws;
  size_t off = 0;
  unsigned short* atomsBf = (unsigned short*)(ws + off); off += (size_t)N_ATOMS * 128 * 2;
  unsigned short* nsum    = (unsigned short*)(ws + off); off += (size_t)N_ATOMS * 128 * 2;  // unused (fused)
  unsigned short* gath    = (unsigned short*)(ws + off); off += (size_t)N_ATOMS * 128 * 2;
  unsigned short* BcatT   = (unsigned short*)(ws + off); off += (size_t)11 * 256 * 256 * 2;
  float* biascat          = (float*)(ws + off);          off += (size_t)11 * 256 * 4;
  (void)nsum;

  // Sort + reduction scratch reuses atomsBf's space (dead after k_gemm):
  char* scr = (char*)atomsBf;
  int* perm      = (int*)(scr);                          // 1.32 MB
  int* hist      = (int*)(scr + 2 * 1024 * 1024);        // 512 B
  int* base_     = (int*)(scr + 2 * 1024 * 1024 + 1024);
  int* blockHist = (int*)(scr + 2 * 1024 * 1024 + 4096); // 128 KB
  int* offTab    = (int*)(scr + 2 * 1024 * 1024 + 4096 + SORT_BLOCKS * BATCH * 4); // 128 KB
  float* psum4   = (float*)(scr + 3 * 1024 * 1024);      // 256 KB
  float* pmax4   = (float*)(scr + 3 * 1024 * 1024 + 256 * 1024);

  float* out0 = (float*)d_out;
  float* out1 = out0 + (size_t)N_ATOMS * 128;
  float* out2 = out1 + 16384;

  hipLaunchKernelGGL(k_cast, dim3(N_ATOMS * 128 / 4 / 256), dim3(256), 0, stream,
                     (const float4*)atoms, (ushort4*)atomsBf);
  hipLaunchKernelGGL(k_build_b, dim3((11 * 256 * 256 + 255) / 256), dim3(256), 0, stream, W, BcatT);
  hipLaunchKernelGGL(k_build_bias, dim3((11 * 256 + 255) / 256), dim3(256), 0, stream, b, biascat);
  hipLaunchKernelGGL(k_gemm, dim3(118, 11), dim3(512), 0, stream,
                     atomsBf, adj, BcatT, biascat, gamma, beta, out0, gath);
  // counting sort (scratch overlays dead atomsBf; zero global atomics)
  hipLaunchKernelGGL(k_hist2, dim3(SORT_BLOCKS), dim3(256), 0, stream, membership, blockHist);
  hipLaunchKernelGGL(k_scan2, dim3(1), dim3(128), 0, stream, blockHist, offTab, base_, hist);
  hipLaunchKernelGGL(k_scatter2, dim3(SORT_BLOCKS), dim3(256), 0, stream, membership, offTab, perm);
  // fused atomic-free segment max + sum
  hipLaunchKernelGGL(k_reduce, dim3(512), dim3(512), 0, stream,
                     (const float2*)out0, (const unsigned*)gath, perm, base_, hist,
                     (float2*)psum4, (float2*)pmax4);
  hipLaunchKernelGGL(k_final, dim3(128), dim3(128), 0, stream,
                     psum4, pmax4, gamma, beta, out1, out2);
}